// Round 1
// baseline (4362.299 us; speedup 1.0000x reference)
//
#include <hip/hip_runtime.h>
#include <cstddef>
#include <cstdint>

// Problem constants (b=2, s=1024)
#define T_TOK   2048      // b*s tokens
#define HID     2048
#define NHEADS  32
#define NKV     8
#define HDIM    64
#define FFN_DIM 8192

// ============================ RMSNorm =====================================
__global__ __launch_bounds__(256) void rmsnorm_kernel(const float* __restrict__ x,
                                                      const float* __restrict__ w,
                                                      float* __restrict__ out)
{
    __shared__ float sm[4];
    const int row = blockIdx.x;
    const int tid = threadIdx.x;
    const float4* xr = (const float4*)(x + (size_t)row * HID);
    float4 a = xr[tid];
    float4 b = xr[tid + 256];
    float ss = a.x*a.x + a.y*a.y + a.z*a.z + a.w*a.w
             + b.x*b.x + b.y*b.y + b.z*b.z + b.w*b.w;
    #pragma unroll
    for (int off = 32; off; off >>= 1) ss += __shfl_down(ss, off, 64);
    if ((tid & 63) == 0) sm[tid >> 6] = ss;
    __syncthreads();
    float tot = sm[0] + sm[1] + sm[2] + sm[3];
    float sc = rsqrtf(tot * (1.0f / HID) + 1e-5f);
    const float4* wr = (const float4*)w;
    float4 w0 = wr[tid], w1 = wr[tid + 256];
    float4* o = (float4*)(out + (size_t)row * HID);
    float4 r0, r1;
    r0.x = a.x * sc * w0.x; r0.y = a.y * sc * w0.y;
    r0.z = a.z * sc * w0.z; r0.w = a.w * sc * w0.w;
    r1.x = b.x * sc * w1.x; r1.y = b.y * sc * w1.y;
    r1.z = b.z * sc * w1.z; r1.w = b.w * sc * w1.w;
    o[tid] = r0; o[tid + 256] = r1;
}

// rms_norm(a + b)  (residual-fused)
__global__ __launch_bounds__(256) void rmsnorm_add_kernel(const float* __restrict__ xa,
                                                          const float* __restrict__ xb,
                                                          const float* __restrict__ w,
                                                          float* __restrict__ out)
{
    __shared__ float sm[4];
    const int row = blockIdx.x;
    const int tid = threadIdx.x;
    const float4* ar = (const float4*)(xa + (size_t)row * HID);
    const float4* br = (const float4*)(xb + (size_t)row * HID);
    float4 a0 = ar[tid], a1 = ar[tid + 256];
    float4 b0 = br[tid], b1 = br[tid + 256];
    float4 s0, s1;
    s0.x = a0.x + b0.x; s0.y = a0.y + b0.y; s0.z = a0.z + b0.z; s0.w = a0.w + b0.w;
    s1.x = a1.x + b1.x; s1.y = a1.y + b1.y; s1.z = a1.z + b1.z; s1.w = a1.w + b1.w;
    float ss = s0.x*s0.x + s0.y*s0.y + s0.z*s0.z + s0.w*s0.w
             + s1.x*s1.x + s1.y*s1.y + s1.z*s1.z + s1.w*s1.w;
    #pragma unroll
    for (int off = 32; off; off >>= 1) ss += __shfl_down(ss, off, 64);
    if ((tid & 63) == 0) sm[tid >> 6] = ss;
    __syncthreads();
    float tot = sm[0] + sm[1] + sm[2] + sm[3];
    float sc = rsqrtf(tot * (1.0f / HID) + 1e-5f);
    const float4* wr = (const float4*)w;
    float4 w0 = wr[tid], w1 = wr[tid + 256];
    float4* o = (float4*)(out + (size_t)row * HID);
    float4 r0, r1;
    r0.x = s0.x * sc * w0.x; r0.y = s0.y * sc * w0.y;
    r0.z = s0.z * sc * w0.z; r0.w = s0.w * sc * w0.w;
    r1.x = s1.x * sc * w1.x; r1.y = s1.y * sc * w1.y;
    r1.z = s1.z * sc * w1.z; r1.w = s1.w * sc * w1.w;
    o[tid] = r0; o[tid + 256] = r1;
}

// ============================ GEMM (fp32, row-major) =======================
// C[M,N] = A[M,K] @ B[K,N]  (+ C if EPI==1). 256 threads. Tile BMxBN, 16 K-step.
template <int BM, int BN, int TM, int TN, int EPI>
__global__ __launch_bounds__(256) void gemm_kernel(const float* __restrict__ A,
                                                   const float* __restrict__ B,
                                                   float* __restrict__ C,
                                                   int M, int N, int K)
{
    constexpr int BK = 16;
    __shared__ float As[BK][BM + 8];   // A^T tile, padded (stride 16B-aligned)
    __shared__ float Bs[BK][BN];
    const int tid = threadIdx.x;
    constexpr int TX = BN / TN;        // threads along N
    const int tx = tid % TX;
    const int ty = tid / TX;
    const float* Ab = A + (size_t)(blockIdx.y * BM) * K;
    const float* Bb = B + (size_t)(blockIdx.x * BN);

    float acc[TM][TN];
    #pragma unroll
    for (int i = 0; i < TM; ++i)
        #pragma unroll
        for (int j = 0; j < TN; ++j) acc[i][j] = 0.0f;

    constexpr int ALOADS = BM * BK / 256;
    constexpr int BLOADS = BN * BK / 256;

    for (int kt = 0; kt < K; kt += BK) {
        #pragma unroll
        for (int l = 0; l < ALOADS; ++l) {
            int e = tid + l * 256;
            int r = e >> 4, c = e & 15;      // BK == 16
            As[c][r] = Ab[(size_t)r * K + kt + c];
        }
        #pragma unroll
        for (int l = 0; l < BLOADS; ++l) {
            int e = tid + l * 256;
            int r = e / BN, c = e % BN;
            Bs[r][c] = Bb[(size_t)(kt + r) * N + c];
        }
        __syncthreads();
        #pragma unroll
        for (int k = 0; k < BK; ++k) {
            float av[TM], bv[TN];
            #pragma unroll
            for (int i = 0; i < TM; i += 4) {
                float4 t4 = *(const float4*)&As[k][ty * TM + i];
                av[i] = t4.x; av[i+1] = t4.y; av[i+2] = t4.z; av[i+3] = t4.w;
            }
            #pragma unroll
            for (int j = 0; j < TN; j += 4) {
                float4 t4 = *(const float4*)&Bs[k][tx * TN + j];
                bv[j] = t4.x; bv[j+1] = t4.y; bv[j+2] = t4.z; bv[j+3] = t4.w;
            }
            #pragma unroll
            for (int i = 0; i < TM; ++i)
                #pragma unroll
                for (int j = 0; j < TN; ++j)
                    acc[i][j] += av[i] * bv[j];
        }
        __syncthreads();
    }

    #pragma unroll
    for (int i = 0; i < TM; ++i) {
        size_t row = (size_t)blockIdx.y * BM + ty * TM + i;
        float* cp = C + row * N + (size_t)blockIdx.x * BN + tx * TN;
        #pragma unroll
        for (int j = 0; j < TN; j += 4) {
            float4 r4;
            r4.x = acc[i][j]; r4.y = acc[i][j+1]; r4.z = acc[i][j+2]; r4.w = acc[i][j+3];
            if (EPI == 1) {
                float4 o = *(const float4*)(cp + j);
                r4.x += o.x; r4.y += o.y; r4.z += o.z; r4.w += o.w;
            }
            *(float4*)(cp + j) = r4;
        }
    }
}

// ============================ RoPE (in place) ==============================
__global__ __launch_bounds__(256) void rope_kernel(float* __restrict__ p,
                                                   const int* __restrict__ pos_ids,
                                                   int nheads)
{
    int idx = blockIdx.x * 256 + threadIdx.x;
    int total = T_TOK * nheads * 32;
    if (idx >= total) return;
    int j = idx & 31;
    int h = (idx >> 5) % nheads;
    int t = idx / (32 * nheads);
    float pos = (float)pos_ids[t];
    float inv = powf(500000.0f, -((float)(2 * j) / 64.0f));
    float ang = pos * inv;
    float c = cosf(ang), s = sinf(ang);
    size_t base = (size_t)t * ((size_t)nheads * HDIM) + (size_t)h * HDIM + j;
    float x1 = p[base], x2 = p[base + 32];
    p[base]      = x1 * c - x2 * s;
    p[base + 32] = x2 * c + x1 * s;
}

// ============================ Flash attention (fp32, causal, GQA) ==========
// grid (4 q-chunks, 32 heads, 2 batches), 256 threads; thread = 1 query row.
__global__ __launch_bounds__(256) void attn_kernel(const float* __restrict__ q,
                                                   const float* __restrict__ k,
                                                   const float* __restrict__ v,
                                                   float* __restrict__ ctx)
{
    __shared__ float Ks[64][64];
    __shared__ float Vs[64][64];
    const int tid = threadIdx.x;
    const int qc = blockIdx.x;
    const int h  = blockIdx.y;
    const int b  = blockIdx.z;
    const int hk = h >> 2;                  // GQA: 4 query heads per KV head
    const int qr = qc * 256 + tid;          // query row within sequence
    const size_t t = (size_t)b * 1024 + qr;

    float qreg[HDIM];
    const float4* qp = (const float4*)(q + t * (NHEADS * HDIM) + (size_t)h * HDIM);
    #pragma unroll
    for (int d4 = 0; d4 < 16; ++d4) {
        float4 vq = qp[d4];
        qreg[d4*4]   = vq.x * 0.125f;       // 1/sqrt(64) folded into q
        qreg[d4*4+1] = vq.y * 0.125f;
        qreg[d4*4+2] = vq.z * 0.125f;
        qreg[d4*4+3] = vq.w * 0.125f;
    }
    float m = -1e30f, l = 0.0f;
    float acc[HDIM];
    #pragma unroll
    for (int d = 0; d < HDIM; ++d) acc[d] = 0.0f;

    const int ntiles = (qc + 1) * 4;        // causal: tiles up to this chunk
    for (int kt = 0; kt < ntiles; ++kt) {
        const float* kb = k + ((size_t)b * 1024 + (size_t)kt * 64) * (NKV * HDIM) + (size_t)hk * HDIM;
        const float* vb = v + ((size_t)b * 1024 + (size_t)kt * 64) * (NKV * HDIM) + (size_t)hk * HDIM;
        #pragma unroll
        for (int l4 = 0; l4 < 4; ++l4) {
            int e = tid + l4 * 256;          // float4-granular: 1024 units
            int r = e >> 4, c4 = e & 15;
            ((float4*)&Ks[r][0])[c4] = ((const float4*)(kb + (size_t)r * (NKV * HDIM)))[c4];
            ((float4*)&Vs[r][0])[c4] = ((const float4*)(vb + (size_t)r * (NKV * HDIM)))[c4];
        }
        __syncthreads();
        int kend = qr - kt * 64 + 1;
        if (kend > 64) kend = 64;
        for (int kk = 0; kk < kend; ++kk) {
            float s = 0.0f;
            #pragma unroll
            for (int d = 0; d < HDIM; ++d) s += qreg[d] * Ks[kk][d];
            float pm = fmaxf(m, s);
            float ex = __expf(s - pm);
            if (pm > m) {
                float sc = __expf(m - pm);
                l *= sc;
                #pragma unroll
                for (int d = 0; d < HDIM; ++d) acc[d] *= sc;
                m = pm;
            }
            l += ex;
            #pragma unroll
            for (int d = 0; d < HDIM; ++d) acc[d] += ex * Vs[kk][d];
        }
        __syncthreads();
    }
    float inv_l = 1.0f / l;
    float4* op = (float4*)(ctx + t * (NHEADS * HDIM) + (size_t)h * HDIM);
    #pragma unroll
    for (int d4 = 0; d4 < 16; ++d4) {
        float4 r4;
        r4.x = acc[d4*4]   * inv_l;
        r4.y = acc[d4*4+1] * inv_l;
        r4.z = acc[d4*4+2] * inv_l;
        r4.w = acc[d4*4+3] * inv_l;
        op[d4] = r4;
    }
}

// ============================ SiLU(g) * u (in place into g) ================
__global__ __launch_bounds__(256) void silu_mul_kernel(float* __restrict__ g,
                                                       const float* __restrict__ u,
                                                       int n4)
{
    int i = blockIdx.x * 256 + threadIdx.x;
    if (i >= n4) return;
    float4 gv = ((const float4*)g)[i];
    float4 uv = ((const float4*)u)[i];
    float4 r;
    r.x = gv.x / (1.0f + __expf(-gv.x)) * uv.x;
    r.y = gv.y / (1.0f + __expf(-gv.y)) * uv.y;
    r.z = gv.z / (1.0f + __expf(-gv.z)) * uv.z;
    r.w = gv.w / (1.0f + __expf(-gv.w)) * uv.w;
    ((float4*)g)[i] = r;
}

// ============================ launch =======================================
extern "C" void kernel_launch(void* const* d_in, const int* in_sizes, int n_in,
                              void* d_out, int out_size, void* d_ws, size_t ws_size,
                              hipStream_t stream)
{
    const float* hidden = (const float*)d_in[0];
    // d_in[1] attention_mask: exactly causal by construction -> handled analytically
    const float* wq = (const float*)d_in[2];
    const float* wk = (const float*)d_in[3];
    const float* wv = (const float*)d_in[4];
    const float* wo = (const float*)d_in[5];
    const float* n1 = (const float*)d_in[6];
    const float* n2 = (const float*)d_in[7];
    const float* wg = (const float*)d_in[8];
    const float* wu = (const float*)d_in[9];
    const float* wd = (const float*)d_in[10];
    const int*  pos = (const int*)d_in[11];
    float* out = (float*)d_out;
    float* ws  = (float*)d_ws;

    // workspace layout (floats)
    float* normed = ws;                       // 2048*2048      (reused for normed_ff)
    float* qb     = ws + 4194304;             // 2048*2048
    float* kb     = ws + 8388608;             // 2048*512
    float* vb     = ws + 9437184;             // 2048*512
    float* ctx    = ws + 10485760;            // 2048*2048
    float* gb     = ws + 14680064;            // 2048*8192      (reused for silu(g)*u)
    float* ub     = ws + 31457280;            // 2048*8192

    // 1. normed = rms_norm(hidden, n1)
    rmsnorm_kernel<<<T_TOK, 256, 0, stream>>>(hidden, n1, normed);
    // 2. q/k/v projections
    gemm_kernel<128,128,8,8,0><<<dim3(HID/128, T_TOK/128), 256, 0, stream>>>(normed, wq, qb, T_TOK, HID, HID);
    gemm_kernel<64,64,4,4,0><<<dim3(512/64,  T_TOK/64), 256, 0, stream>>>(normed, wk, kb, T_TOK, 512, HID);
    gemm_kernel<64,64,4,4,0><<<dim3(512/64,  T_TOK/64), 256, 0, stream>>>(normed, wv, vb, T_TOK, 512, HID);
    // 3. RoPE in place
    rope_kernel<<<(T_TOK*NHEADS*32 + 255)/256, 256, 0, stream>>>(qb, pos, NHEADS);
    rope_kernel<<<(T_TOK*NKV*32 + 255)/256, 256, 0, stream>>>(kb, pos, NKV);
    // 4. causal GQA attention
    attn_kernel<<<dim3(4, NHEADS, 2), 256, 0, stream>>>(qb, kb, vb, ctx);
    // 5. attn_out = ctx @ wo  -> d_out
    gemm_kernel<128,128,8,8,0><<<dim3(HID/128, T_TOK/128), 256, 0, stream>>>(ctx, wo, out, T_TOK, HID, HID);
    // 6. normed_ff = rms_norm(attn_out + hidden, n2)
    rmsnorm_add_kernel<<<T_TOK, 256, 0, stream>>>(out, hidden, n2, normed);
    // 7. gate & up
    gemm_kernel<128,128,8,8,0><<<dim3(FFN_DIM/128, T_TOK/128), 256, 0, stream>>>(normed, wg, gb, T_TOK, FFN_DIM, HID);
    gemm_kernel<128,128,8,8,0><<<dim3(FFN_DIM/128, T_TOK/128), 256, 0, stream>>>(normed, wu, ub, T_TOK, FFN_DIM, HID);
    // 8. h = silu(g) * u
    silu_mul_kernel<<<(T_TOK*FFN_DIM/4 + 255)/256, 256, 0, stream>>>(gb, ub, T_TOK*FFN_DIM/4);
    // 9. out = h @ wd + attn_out(d_out)
    gemm_kernel<128,128,8,8,1><<<dim3(HID/128, T_TOK/128), 256, 0, stream>>>(gb, wd, out, T_TOK, HID, FFN_DIM);
}

// Round 2
// 1175.259 us; speedup vs baseline: 3.7118x; 3.7118x over previous
//
#include <hip/hip_runtime.h>
#include <hip/hip_bf16.h>
#include <cstddef>
#include <cstdint>

#define T_TOK   2048
#define HID     2048
#define NHEADS  32
#define NKV     8
#define HDIM    64
#define FFN_DIM 8192
#define QKV_N   3072

typedef __hip_bfloat16 bf16;
typedef __attribute__((ext_vector_type(8))) short short8;
typedef __attribute__((ext_vector_type(4))) float f32x4;

typedef __attribute__((address_space(1))) const void cg_void;
typedef __attribute__((address_space(3))) void lds_void;

// ===================== cast + transpose: W[K][N] f32 -> Wt[N][K] bf16 ======
__global__ __launch_bounds__(256) void cast_transpose(const float* __restrict__ in,
                                                      bf16* __restrict__ out,
                                                      int K, int N)
{
    __shared__ bf16 t[64][65];
    const int n0 = blockIdx.x * 64, k0 = blockIdx.y * 64;
    const int tn = threadIdx.x & 63, tk = threadIdx.x >> 6;
    #pragma unroll
    for (int kk = tk; kk < 64; kk += 4)
        t[kk][tn] = __float2bfloat16(in[(size_t)(k0 + kk) * N + n0 + tn]);
    __syncthreads();
    #pragma unroll
    for (int nn = tk; nn < 64; nn += 4)
        out[(size_t)(n0 + nn) * K + k0 + tn] = t[tn][nn];
}

// ===================== RMSNorm (f32 in -> bf16 out) ========================
__global__ __launch_bounds__(256) void rmsnorm_kernel(const float* __restrict__ x,
                                                      const float* __restrict__ w,
                                                      bf16* __restrict__ out)
{
    __shared__ float sm[4];
    const int row = blockIdx.x, tid = threadIdx.x;
    const float4* xr = (const float4*)(x + (size_t)row * HID);
    float4 a = xr[tid], b = xr[tid + 256];
    float ss = a.x*a.x + a.y*a.y + a.z*a.z + a.w*a.w
             + b.x*b.x + b.y*b.y + b.z*b.z + b.w*b.w;
    #pragma unroll
    for (int off = 32; off; off >>= 1) ss += __shfl_down(ss, off);
    if ((tid & 63) == 0) sm[tid >> 6] = ss;
    __syncthreads();
    float sc = rsqrtf((sm[0] + sm[1] + sm[2] + sm[3]) * (1.0f / HID) + 1e-5f);
    const float4* wr = (const float4*)w;
    float4 w0 = wr[tid], w1 = wr[tid + 256];
    bf16* o = out + (size_t)row * HID;
    o[tid*4+0] = __float2bfloat16(a.x * sc * w0.x);
    o[tid*4+1] = __float2bfloat16(a.y * sc * w0.y);
    o[tid*4+2] = __float2bfloat16(a.z * sc * w0.z);
    o[tid*4+3] = __float2bfloat16(a.w * sc * w0.w);
    o[1024+tid*4+0] = __float2bfloat16(b.x * sc * w1.x);
    o[1024+tid*4+1] = __float2bfloat16(b.y * sc * w1.y);
    o[1024+tid*4+2] = __float2bfloat16(b.z * sc * w1.z);
    o[1024+tid*4+3] = __float2bfloat16(b.w * sc * w1.w);
}

// rms_norm(a + b) -> bf16
__global__ __launch_bounds__(256) void rmsnorm_add_kernel(const float* __restrict__ xa,
                                                          const float* __restrict__ xb,
                                                          const float* __restrict__ w,
                                                          bf16* __restrict__ out)
{
    __shared__ float sm[4];
    const int row = blockIdx.x, tid = threadIdx.x;
    const float4* ar = (const float4*)(xa + (size_t)row * HID);
    const float4* br = (const float4*)(xb + (size_t)row * HID);
    float4 a0 = ar[tid], a1 = ar[tid + 256];
    float4 b0 = br[tid], b1 = br[tid + 256];
    float4 s0, s1;
    s0.x = a0.x + b0.x; s0.y = a0.y + b0.y; s0.z = a0.z + b0.z; s0.w = a0.w + b0.w;
    s1.x = a1.x + b1.x; s1.y = a1.y + b1.y; s1.z = a1.z + b1.z; s1.w = a1.w + b1.w;
    float ss = s0.x*s0.x + s0.y*s0.y + s0.z*s0.z + s0.w*s0.w
             + s1.x*s1.x + s1.y*s1.y + s1.z*s1.z + s1.w*s1.w;
    #pragma unroll
    for (int off = 32; off; off >>= 1) ss += __shfl_down(ss, off);
    if ((tid & 63) == 0) sm[tid >> 6] = ss;
    __syncthreads();
    float sc = rsqrtf((sm[0] + sm[1] + sm[2] + sm[3]) * (1.0f / HID) + 1e-5f);
    const float4* wr = (const float4*)w;
    float4 w0 = wr[tid], w1 = wr[tid + 256];
    bf16* o = out + (size_t)row * HID;
    o[tid*4+0] = __float2bfloat16(s0.x * sc * w0.x);
    o[tid*4+1] = __float2bfloat16(s0.y * sc * w0.y);
    o[tid*4+2] = __float2bfloat16(s0.z * sc * w0.z);
    o[tid*4+3] = __float2bfloat16(s0.w * sc * w0.w);
    o[1024+tid*4+0] = __float2bfloat16(s1.x * sc * w1.x);
    o[1024+tid*4+1] = __float2bfloat16(s1.y * sc * w1.y);
    o[1024+tid*4+2] = __float2bfloat16(s1.z * sc * w1.z);
    o[1024+tid*4+3] = __float2bfloat16(s1.w * sc * w1.w);
}

// ===================== MFMA GEMM: C[M][N] = A[M][K] @ Bt[N][K]^T ===========
// m97 structure: 128x128 tile, BK=64, 4 waves (2x2), 4x4 frags of 16x16x32.
// global_load_lds width=16 with pre-swizzled global source (rule #21):
// LDS linear dest, lane fetches k-chunk (ln&7)^(row&7); reads XOR the same.
// EPI: 0 = f32 store, 1 = f32 +=, 2 = bf16 silu(acc), 3 = bf16 aux*acc
template<int EPI>
__global__ __launch_bounds__(256) void mfma_gemm(
    const bf16* __restrict__ A, const bf16* __restrict__ Bt,
    float* __restrict__ Cf, bf16* __restrict__ Cb, const bf16* __restrict__ aux,
    int M, int N, int K, int ldc, int ldaux)
{
    __shared__ bf16 As[128 * 64];
    __shared__ bf16 Bs[128 * 64];
    const int tid = threadIdx.x;
    const int wv = tid >> 6, ln = tid & 63;
    const int wr = wv >> 1, wc = wv & 1;
    const size_t m0 = (size_t)blockIdx.y * 128;
    const size_t n0 = (size_t)blockIdx.x * 128;

    const int lrow = ln >> 3;              // row within 8-row chunk
    const int lk   = (ln & 7) ^ lrow;      // swizzled k-chunk (inverse-swz source)
    const int qa   = wv * 4;               // this wave's first chunk

    f32x4 acc[4][4] = {};

    const bf16* Abase = A  + (m0 + (size_t)qa*8 + lrow) * K + lk*8;
    const bf16* Bbase = Bt + (n0 + (size_t)qa*8 + lrow) * K + lk*8;
    bf16* AsW = As + qa * 512;
    bf16* BsW = Bs + qa * 512;

    for (int kt = 0; kt < K; kt += 64) {
        #pragma unroll
        for (int i = 0; i < 4; ++i) {
            __builtin_amdgcn_global_load_lds((cg_void*)(Abase + (size_t)i*8*K + kt),
                                             (lds_void*)(AsW + i*512), 16, 0, 0);
            __builtin_amdgcn_global_load_lds((cg_void*)(Bbase + (size_t)i*8*K + kt),
                                             (lds_void*)(BsW + i*512), 16, 0, 0);
        }
        __syncthreads();
        #pragma unroll
        for (int ks = 0; ks < 2; ++ks) {
            short8 af[4], bfg[4];
            const int kbyte = ks*64 + (ln >> 4)*16;
            #pragma unroll
            for (int m = 0; m < 4; ++m) {
                int row = wr*64 + m*16 + (ln & 15);
                af[m] = *(const short8*)((const char*)As + row*128 + (kbyte ^ ((row & 7) << 4)));
            }
            #pragma unroll
            for (int n = 0; n < 4; ++n) {
                int row = wc*64 + n*16 + (ln & 15);
                bfg[n] = *(const short8*)((const char*)Bs + row*128 + (kbyte ^ ((row & 7) << 4)));
            }
            #pragma unroll
            for (int m = 0; m < 4; ++m)
                #pragma unroll
                for (int n = 0; n < 4; ++n)
                    acc[m][n] = __builtin_amdgcn_mfma_f32_16x16x32_bf16(af[m], bfg[n], acc[m][n], 0, 0, 0);
        }
        __syncthreads();
    }

    // C/D layout: col = lane&15, row = (lane>>4)*4 + reg  [m89/m91 verified]
    const int cj = ln & 15, rj = ln >> 4;
    #pragma unroll
    for (int m = 0; m < 4; ++m) {
        #pragma unroll
        for (int j = 0; j < 4; ++j) {
            size_t row = m0 + wr*64 + m*16 + rj*4 + j;
            #pragma unroll
            for (int n = 0; n < 4; ++n) {
                int col = (int)n0 + wc*64 + n*16 + cj;
                float v = acc[m][n][j];
                size_t off = row * (size_t)ldc + col;
                if constexpr (EPI == 0) {
                    Cf[off] = v;
                } else if constexpr (EPI == 1) {
                    Cf[off] += v;
                } else if constexpr (EPI == 2) {
                    Cb[off] = __float2bfloat16(v / (1.0f + __expf(-v)));
                } else {
                    float g = __bfloat162float(aux[row * (size_t)ldaux + col]);
                    Cb[off] = __float2bfloat16(g * v);
                }
            }
        }
    }
}

// ===================== RoPE on fused qkv (in place, f32) ===================
__global__ __launch_bounds__(256) void rope_kernel(float* __restrict__ qkv,
                                                   const int* __restrict__ pos_ids)
{
    int idx = blockIdx.x * 256 + threadIdx.x;
    const int total = T_TOK * 40 * 32;           // 32 q-heads + 8 k-heads
    if (idx >= total) return;
    int j  = idx & 31;
    int hs = (idx >> 5) % 40;
    int t  = idx / (32 * 40);
    int col = (hs < 32) ? hs * 64 + j : HID + (hs - 32) * 64 + j;
    float pos = (float)pos_ids[t];
    float inv = exp2f(-(float)j * 0.5916115177913804f);   // log2(5e5)/32
    float ang = pos * inv;
    float c, s;
    sincosf(ang, &s, &c);
    size_t base = (size_t)t * QKV_N + col;
    float x1 = qkv[base], x2 = qkv[base + 32];
    qkv[base]      = x1 * c - x2 * s;
    qkv[base + 32] = x2 * c + x1 * s;
}

// ===================== Flash attention (f32, causal, GQA) ==================
__global__ __launch_bounds__(256) void attn_kernel(const float* __restrict__ qkv,
                                                   bf16* __restrict__ ctx)
{
    __shared__ float Ks[64][64];
    __shared__ float Vs[64][64];
    const int tid = threadIdx.x;
    const int qc = blockIdx.x;
    const int h  = blockIdx.y;
    const int b  = blockIdx.z;
    const int hk = h >> 2;
    const int qr = qc * 256 + tid;
    const size_t t = (size_t)b * 1024 + qr;

    float qreg[HDIM];
    const float4* qp = (const float4*)(qkv + t * QKV_N + (size_t)h * HDIM);
    #pragma unroll
    for (int d4 = 0; d4 < 16; ++d4) {
        float4 vq = qp[d4];
        qreg[d4*4]   = vq.x * 0.125f;
        qreg[d4*4+1] = vq.y * 0.125f;
        qreg[d4*4+2] = vq.z * 0.125f;
        qreg[d4*4+3] = vq.w * 0.125f;
    }
    float m = -1e30f, l = 0.0f;
    float acc[HDIM];
    #pragma unroll
    for (int d = 0; d < HDIM; ++d) acc[d] = 0.0f;

    const int ntiles = (qc + 1) * 4;
    for (int kt = 0; kt < ntiles; ++kt) {
        const float* kb = qkv + ((size_t)b * 1024 + (size_t)kt * 64) * QKV_N + HID + (size_t)hk * HDIM;
        const float* vb = kb + NKV * HDIM;   // v section is 512 floats after k
        #pragma unroll
        for (int l4 = 0; l4 < 4; ++l4) {
            int e = tid + l4 * 256;
            int r = e >> 4, c4 = e & 15;
            ((float4*)&Ks[r][0])[c4] = ((const float4*)(kb + (size_t)r * QKV_N))[c4];
            ((float4*)&Vs[r][0])[c4] = ((const float4*)(vb + (size_t)r * QKV_N))[c4];
        }
        __syncthreads();
        int kend = qr - kt * 64 + 1;
        if (kend > 64) kend = 64;
        for (int kk = 0; kk < kend; ++kk) {
            float s = 0.0f;
            #pragma unroll
            for (int d = 0; d < HDIM; ++d) s += qreg[d] * Ks[kk][d];
            float pm = fmaxf(m, s);
            float ex = __expf(s - pm);
            if (pm > m) {
                float sc = __expf(m - pm);
                l *= sc;
                #pragma unroll
                for (int d = 0; d < HDIM; ++d) acc[d] *= sc;
                m = pm;
            }
            l += ex;
            #pragma unroll
            for (int d = 0; d < HDIM; ++d) acc[d] += ex * Vs[kk][d];
        }
        __syncthreads();
    }
    float inv_l = 1.0f / l;
    bf16* op = ctx + t * HID + (size_t)h * HDIM;
    #pragma unroll
    for (int d = 0; d < HDIM; ++d) op[d] = __float2bfloat16(acc[d] * inv_l);
}

// ===================== launch ==============================================
extern "C" void kernel_launch(void* const* d_in, const int* in_sizes, int n_in,
                              void* d_out, int out_size, void* d_ws, size_t ws_size,
                              hipStream_t stream)
{
    const float* hidden = (const float*)d_in[0];
    const float* wq = (const float*)d_in[2];
    const float* wk = (const float*)d_in[3];
    const float* wv = (const float*)d_in[4];
    const float* wo = (const float*)d_in[5];
    const float* n1 = (const float*)d_in[6];
    const float* n2 = (const float*)d_in[7];
    const float* wg = (const float*)d_in[8];
    const float* wu = (const float*)d_in[9];
    const float* wd = (const float*)d_in[10];
    const int*  pos = (const int*)d_in[11];
    float* out = (float*)d_out;
    char* ws = (char*)d_ws;

    // workspace layout (byte offsets; max 180,355,072 B < 193 MB proven)
    bf16* wg_t   = (bf16*)(ws + 0);           // [8192][2048]  33.55 MB
    bf16* wu_t   = (bf16*)(ws + 33554432);    // [8192][2048]  33.55 MB
    bf16* wd_t   = (bf16*)(ws + 67108864);    // [2048][8192]  33.55 MB
    bf16* wqkv_t = (bf16*)(ws + 100663296);   // [3072][2048]  12.58 MB
    bf16* wo_t   = (bf16*)(ws + 113246208);   // [2048][2048]   8.39 MB
    bf16* normed = (bf16*)(ws + 121634816);   // [2048][2048]   8.39 MB (reused)
    float* qkv   = (float*)(ws + 130023424);  // [2048][3072]  25.17 MB
    bf16* ctx    = (bf16*)(ws + 155189248);   // [2048][2048]   8.39 MB
    bf16* hb     = (bf16*)(ws + 130023424);   // [2048][8192]  aliases qkv+ctx (dead)
    bf16* gbh    = (bf16*)(ws + 163577856);   // [2048][4096]  16.78 MB

    // weight casts (per call; deterministic)
    cast_transpose<<<dim3(32, 32), 256, 0, stream>>>(wq, wqkv_t, 2048, 2048);
    cast_transpose<<<dim3(8, 32),  256, 0, stream>>>(wk, wqkv_t + 4194304, 2048, 512);
    cast_transpose<<<dim3(8, 32),  256, 0, stream>>>(wv, wqkv_t + 5242880, 2048, 512);
    cast_transpose<<<dim3(32, 32), 256, 0, stream>>>(wo, wo_t, 2048, 2048);
    cast_transpose<<<dim3(128, 32),256, 0, stream>>>(wg, wg_t, 2048, 8192);
    cast_transpose<<<dim3(128, 32),256, 0, stream>>>(wu, wu_t, 2048, 8192);
    cast_transpose<<<dim3(32, 128),256, 0, stream>>>(wd, wd_t, 8192, 2048);

    // 1. normed = rms_norm(hidden) (bf16)
    rmsnorm_kernel<<<T_TOK, 256, 0, stream>>>(hidden, n1, normed);
    // 2. fused qkv = normed @ [wq|wk|wv]  (f32 out)
    mfma_gemm<0><<<dim3(QKV_N/128, T_TOK/128), 256, 0, stream>>>(
        normed, wqkv_t, qkv, nullptr, nullptr, T_TOK, QKV_N, HID, QKV_N, 0);
    // 3. RoPE in place on q,k sections
    rope_kernel<<<(T_TOK*40*32 + 255)/256, 256, 0, stream>>>(qkv, pos);
    // 4. causal GQA attention -> ctx (bf16)
    attn_kernel<<<dim3(4, NHEADS, 2), 256, 0, stream>>>(qkv, ctx);
    // 5. attn_out = ctx @ wo -> d_out (f32)
    mfma_gemm<0><<<dim3(HID/128, T_TOK/128), 256, 0, stream>>>(
        ctx, wo_t, out, nullptr, nullptr, T_TOK, HID, HID, HID, 0);
    // 6. normed2 = rms_norm(attn_out + hidden) (bf16, reuses normed)
    rmsnorm_add_kernel<<<T_TOK, 256, 0, stream>>>(out, hidden, n2, normed);
    // 7-8. FFN in two N-halves: gate (silu fused) then up (mul fused) -> hb bf16
    for (int hh = 0; hh < 2; ++hh) {
        mfma_gemm<2><<<dim3(4096/128, T_TOK/128), 256, 0, stream>>>(
            normed, wg_t + (size_t)hh*4096*2048, nullptr, gbh, nullptr,
            T_TOK, 4096, HID, 4096, 0);
        mfma_gemm<3><<<dim3(4096/128, T_TOK/128), 256, 0, stream>>>(
            normed, wu_t + (size_t)hh*4096*2048, nullptr, hb + (size_t)hh*4096, gbh,
            T_TOK, 4096, HID, 8192, 4096);
    }
    // 9. d_out += hb @ wd
    mfma_gemm<1><<<dim3(HID/128, T_TOK/128), 256, 0, stream>>>(
        hb, wd_t, out, nullptr, nullptr, T_TOK, HID, FFN_DIM, HID, 0);
}

// Round 3
// 645.345 us; speedup vs baseline: 6.7596x; 1.8211x over previous
//
#include <hip/hip_runtime.h>
#include <hip/hip_bf16.h>
#include <cstddef>
#include <cstdint>

#define T_TOK   2048
#define HID     2048
#define NHEADS  32
#define NKV     8
#define HDIM    64
#define FFN_DIM 8192
#define QKV_N   3072

typedef __hip_bfloat16 bf16;
typedef __attribute__((ext_vector_type(8))) short short8;
typedef __attribute__((ext_vector_type(4))) float f32x4;
typedef __attribute__((ext_vector_type(4))) unsigned short us4;

typedef __attribute__((address_space(1))) const void cg_void;
typedef __attribute__((address_space(3))) void lds_void;

// ===================== cast + transpose: W[K][N] f32 -> Wt[N][K] bf16 ======
__global__ __launch_bounds__(256) void cast_transpose(const float* __restrict__ in,
                                                      bf16* __restrict__ out,
                                                      int K, int N)
{
    __shared__ bf16 t[64][65];
    const int n0 = blockIdx.x * 64, k0 = blockIdx.y * 64;
    const int tn = threadIdx.x & 63, tk = threadIdx.x >> 6;
    #pragma unroll
    for (int kk = tk; kk < 64; kk += 4)
        t[kk][tn] = __float2bfloat16(in[(size_t)(k0 + kk) * N + n0 + tn]);
    __syncthreads();
    #pragma unroll
    for (int nn = tk; nn < 64; nn += 4)
        out[(size_t)(n0 + nn) * K + k0 + tn] = t[tn][nn];
}

// ===================== RMSNorm (f32 in -> bf16 out) ========================
__global__ __launch_bounds__(256) void rmsnorm_kernel(const float* __restrict__ x,
                                                      const float* __restrict__ w,
                                                      bf16* __restrict__ out)
{
    __shared__ float sm[4];
    const int row = blockIdx.x, tid = threadIdx.x;
    const float4* xr = (const float4*)(x + (size_t)row * HID);
    float4 a = xr[tid], b = xr[tid + 256];
    float ss = a.x*a.x + a.y*a.y + a.z*a.z + a.w*a.w
             + b.x*b.x + b.y*b.y + b.z*b.z + b.w*b.w;
    #pragma unroll
    for (int off = 32; off; off >>= 1) ss += __shfl_down(ss, off);
    if ((tid & 63) == 0) sm[tid >> 6] = ss;
    __syncthreads();
    float sc = rsqrtf((sm[0] + sm[1] + sm[2] + sm[3]) * (1.0f / HID) + 1e-5f);
    const float4* wr = (const float4*)w;
    float4 w0 = wr[tid], w1 = wr[tid + 256];
    bf16* o = out + (size_t)row * HID;
    o[tid*4+0] = __float2bfloat16(a.x * sc * w0.x);
    o[tid*4+1] = __float2bfloat16(a.y * sc * w0.y);
    o[tid*4+2] = __float2bfloat16(a.z * sc * w0.z);
    o[tid*4+3] = __float2bfloat16(a.w * sc * w0.w);
    o[1024+tid*4+0] = __float2bfloat16(b.x * sc * w1.x);
    o[1024+tid*4+1] = __float2bfloat16(b.y * sc * w1.y);
    o[1024+tid*4+2] = __float2bfloat16(b.z * sc * w1.z);
    o[1024+tid*4+3] = __float2bfloat16(b.w * sc * w1.w);
}

// rms_norm(a + b) -> bf16
__global__ __launch_bounds__(256) void rmsnorm_add_kernel(const float* __restrict__ xa,
                                                          const float* __restrict__ xb,
                                                          const float* __restrict__ w,
                                                          bf16* __restrict__ out)
{
    __shared__ float sm[4];
    const int row = blockIdx.x, tid = threadIdx.x;
    const float4* ar = (const float4*)(xa + (size_t)row * HID);
    const float4* br = (const float4*)(xb + (size_t)row * HID);
    float4 a0 = ar[tid], a1 = ar[tid + 256];
    float4 b0 = br[tid], b1 = br[tid + 256];
    float4 s0, s1;
    s0.x = a0.x + b0.x; s0.y = a0.y + b0.y; s0.z = a0.z + b0.z; s0.w = a0.w + b0.w;
    s1.x = a1.x + b1.x; s1.y = a1.y + b1.y; s1.z = a1.z + b1.z; s1.w = a1.w + b1.w;
    float ss = s0.x*s0.x + s0.y*s0.y + s0.z*s0.z + s0.w*s0.w
             + s1.x*s1.x + s1.y*s1.y + s1.z*s1.z + s1.w*s1.w;
    #pragma unroll
    for (int off = 32; off; off >>= 1) ss += __shfl_down(ss, off);
    if ((tid & 63) == 0) sm[tid >> 6] = ss;
    __syncthreads();
    float sc = rsqrtf((sm[0] + sm[1] + sm[2] + sm[3]) * (1.0f / HID) + 1e-5f);
    const float4* wr = (const float4*)w;
    float4 w0 = wr[tid], w1 = wr[tid + 256];
    bf16* o = out + (size_t)row * HID;
    o[tid*4+0] = __float2bfloat16(s0.x * sc * w0.x);
    o[tid*4+1] = __float2bfloat16(s0.y * sc * w0.y);
    o[tid*4+2] = __float2bfloat16(s0.z * sc * w0.z);
    o[tid*4+3] = __float2bfloat16(s0.w * sc * w0.w);
    o[1024+tid*4+0] = __float2bfloat16(s1.x * sc * w1.x);
    o[1024+tid*4+1] = __float2bfloat16(s1.y * sc * w1.y);
    o[1024+tid*4+2] = __float2bfloat16(s1.z * sc * w1.z);
    o[1024+tid*4+3] = __float2bfloat16(s1.w * sc * w1.w);
}

// ===================== MFMA GEMM: C[M][N] = A[M][K] @ Bt[N][K]^T ===========
// EPI: 0 = f32 store, 1 = f32 +=, 2 = bf16 silu(acc), 3 = bf16 aux*acc
template<int EPI>
__global__ __launch_bounds__(256) void mfma_gemm(
    const bf16* __restrict__ A, const bf16* __restrict__ Bt,
    float* __restrict__ Cf, bf16* __restrict__ Cb, const bf16* __restrict__ aux,
    int M, int N, int K, int ldc, int ldaux)
{
    __shared__ bf16 As[128 * 64];
    __shared__ bf16 Bs[128 * 64];
    const int tid = threadIdx.x;
    const int wv = tid >> 6, ln = tid & 63;
    const int wr = wv >> 1, wc = wv & 1;
    const size_t m0 = (size_t)blockIdx.y * 128;
    const size_t n0 = (size_t)blockIdx.x * 128;

    const int lrow = ln >> 3;
    const int lk   = (ln & 7) ^ lrow;
    const int qa   = wv * 4;

    f32x4 acc[4][4] = {};

    const bf16* Abase = A  + (m0 + (size_t)qa*8 + lrow) * K + lk*8;
    const bf16* Bbase = Bt + (n0 + (size_t)qa*8 + lrow) * K + lk*8;
    bf16* AsW = As + qa * 512;
    bf16* BsW = Bs + qa * 512;

    for (int kt = 0; kt < K; kt += 64) {
        #pragma unroll
        for (int i = 0; i < 4; ++i) {
            __builtin_amdgcn_global_load_lds((cg_void*)(Abase + (size_t)i*8*K + kt),
                                             (lds_void*)(AsW + i*512), 16, 0, 0);
            __builtin_amdgcn_global_load_lds((cg_void*)(Bbase + (size_t)i*8*K + kt),
                                             (lds_void*)(BsW + i*512), 16, 0, 0);
        }
        __syncthreads();
        #pragma unroll
        for (int ks = 0; ks < 2; ++ks) {
            short8 af[4], bfg[4];
            const int kbyte = ks*64 + (ln >> 4)*16;
            #pragma unroll
            for (int m = 0; m < 4; ++m) {
                int row = wr*64 + m*16 + (ln & 15);
                af[m] = *(const short8*)((const char*)As + row*128 + (kbyte ^ ((row & 7) << 4)));
            }
            #pragma unroll
            for (int n = 0; n < 4; ++n) {
                int row = wc*64 + n*16 + (ln & 15);
                bfg[n] = *(const short8*)((const char*)Bs + row*128 + (kbyte ^ ((row & 7) << 4)));
            }
            #pragma unroll
            for (int m = 0; m < 4; ++m)
                #pragma unroll
                for (int n = 0; n < 4; ++n)
                    acc[m][n] = __builtin_amdgcn_mfma_f32_16x16x32_bf16(af[m], bfg[n], acc[m][n], 0, 0, 0);
        }
        __syncthreads();
    }

    const int cj = ln & 15, rj = ln >> 4;
    #pragma unroll
    for (int m = 0; m < 4; ++m) {
        #pragma unroll
        for (int j = 0; j < 4; ++j) {
            size_t row = m0 + wr*64 + m*16 + rj*4 + j;
            #pragma unroll
            for (int n = 0; n < 4; ++n) {
                int col = (int)n0 + wc*64 + n*16 + cj;
                float v = acc[m][n][j];
                size_t off = row * (size_t)ldc + col;
                if constexpr (EPI == 0) {
                    Cf[off] = v;
                } else if constexpr (EPI == 1) {
                    Cf[off] += v;
                } else if constexpr (EPI == 2) {
                    Cb[off] = __float2bfloat16(v / (1.0f + __expf(-v)));
                } else {
                    float g = __bfloat162float(aux[row * (size_t)ldaux + col]);
                    Cb[off] = __float2bfloat16(g * v);
                }
            }
        }
    }
}

// ===================== RoPE + cast: qkv f32 -> Qp/Kp bf16 (head-major) =====
// Qp: [2][32][1024][64], Kp: [2][8][1024][64]
__global__ __launch_bounds__(256) void rope_cast(const float* __restrict__ qkv,
                                                 const int* __restrict__ pos_ids,
                                                 bf16* __restrict__ Qp,
                                                 bf16* __restrict__ Kp)
{
    const int t = blockIdx.x, tid = threadIdx.x;
    const int b = t >> 10, s = t & 1023;
    const float pos = (float)pos_ids[t];
    const float* row = qkv + (size_t)t * QKV_N;

    // Q: 1024 rotation pairs; 4 per thread (same head, consecutive j)
    {
        int idx = tid * 4;
        int hq = idx >> 5, j = idx & 31;
        float xa[4], xb[4];
        *(float4*)xa = *(const float4*)(row + hq*64 + j);
        *(float4*)xb = *(const float4*)(row + hq*64 + j + 32);
        us4 o1, o2;
        #pragma unroll
        for (int jj = 0; jj < 4; ++jj) {
            float inv = exp2f(-(float)(j + jj) * 0.5916115177913804f);
            float ang = pos * inv, c, sn;
            sincosf(ang, &sn, &c);
            o1[jj] = __bfloat16_as_ushort(__float2bfloat16(xa[jj]*c - xb[jj]*sn));
            o2[jj] = __bfloat16_as_ushort(__float2bfloat16(xb[jj]*c + xa[jj]*sn));
        }
        bf16* qd = Qp + ((size_t)(b*32 + hq)*1024 + s)*64;
        *(us4*)(qd + j)      = o1;
        *(us4*)(qd + j + 32) = o2;
    }
    // K: 256 rotation pairs; 1 per thread
    {
        int hk = tid >> 5, j = tid & 31;
        float a = row[2048 + hk*64 + j];
        float bb = row[2048 + hk*64 + j + 32];
        float inv = exp2f(-(float)j * 0.5916115177913804f);
        float ang = pos * inv, c, sn;
        sincosf(ang, &sn, &c);
        bf16* kd = Kp + ((size_t)(b*8 + hk)*1024 + s)*64;
        kd[j]      = __float2bfloat16(a*c - bb*sn);
        kd[j + 32] = __float2bfloat16(bb*c + a*sn);
    }
}

// ===================== V transpose+cast: qkv f32 -> Vt[16][64][1024] bf16 ==
__global__ __launch_bounds__(256) void vt_cast(const float* __restrict__ qkv,
                                               bf16* __restrict__ Vt)
{
    __shared__ bf16 tile[64][64];
    const int s0 = blockIdx.x * 64;
    const int sec = blockIdx.y;                 // b*8 + hk
    const int b = sec >> 3, hk = sec & 7;
    const int tid = threadIdx.x;
    const float* base = qkv + ((size_t)(b*1024 + s0)) * QKV_N + 2560 + hk*64;
    const int srow = tid >> 2, d0 = (tid & 3) * 16;
    #pragma unroll
    for (int q = 0; q < 4; ++q) {
        float va[4];
        *(float4*)va = *(const float4*)(base + (size_t)srow * QKV_N + d0 + q*4);
        #pragma unroll
        for (int cc = 0; cc < 4; ++cc)
            tile[d0 + q*4 + cc][srow] = __float2bfloat16(va[cc]);
    }
    __syncthreads();
    const int dr = tid >> 2, sc = (tid & 3) * 16;
    bf16* od = Vt + ((size_t)sec*64 + dr)*1024 + s0 + sc;
    *(short8*)od       = *(const short8*)&tile[dr][sc];
    *(short8*)(od + 8) = *(const short8*)&tile[dr][sc + 8];
}

// ===================== MFMA flash attention (bf16, causal, GQA) ============
// grid (8 q-tiles, 32 heads, 2 b); 4 waves; wave owns 32 q-rows; KVBLK=128.
__global__ __launch_bounds__(256) void attn_mfma(const bf16* __restrict__ Qp,
                                                 const bf16* __restrict__ Kp,
                                                 const bf16* __restrict__ Vt,
                                                 bf16* __restrict__ ctx)
{
    __shared__ bf16 Ks[128 * 64];       // [kv][d]  swizzled, 16KB
    __shared__ bf16 Vs[64 * 128];       // [d][kv]  swizzled, 16KB
    __shared__ bf16 Ps[4 * 32 * 128];   // per-wave [32 q][128 kv] swizzled, 32KB
    const int tid = threadIdx.x;
    const int w = tid >> 6, ln = tid & 63;
    const int qt = blockIdx.x, h = blockIdx.y, b = blockIdx.z;
    const int hk = h >> 2;
    const int q0 = qt * 128;

    const bf16* qsec = Qp + ((size_t)(b*32 + h)*1024 + q0 + w*32)*64;
    const bf16* ksec = Kp + ((size_t)(b*8 + hk)*1024)*64;
    const bf16* vsec = Vt + ((size_t)(b*8 + hk))*64*1024;

    // Q fragments (A-layout): lane holds Q[f*16+(ln&15)][kc*32+(ln>>4)*8 ..+7]
    short8 qf[2][2];
    #pragma unroll
    for (int f = 0; f < 2; ++f)
        #pragma unroll
        for (int kc = 0; kc < 2; ++kc)
            qf[f][kc] = *(const short8*)(qsec + (size_t)(f*16 + (ln & 15))*64 + kc*32 + (ln >> 4)*8);

    f32x4 acc_o[2][4] = {};
    f32x4 m[2], l[2];
    #pragma unroll
    for (int f = 0; f < 2; ++f)
        #pragma unroll
        for (int j = 0; j < 4; ++j) { m[f][j] = -1e30f; l[f][j] = 0.0f; }

    const int lrow = ln >> 3;
    const int lkk  = (ln & 7) ^ lrow;
    char* PsW = (char*)Ps + w * 8192;

    const int ntiles = qt + 1;
    for (int kt = 0; kt < ntiles; ++kt) {
        const int kv0 = kt * 128;
        // stage K tile [128][64] (wave w: rows w*32..+31), swizzled source
        {
            const bf16* kbase = ksec + (size_t)(kv0 + w*32 + lrow)*64 + lkk*8;
            bf16* KsW = Ks + w*2048;
            #pragma unroll
            for (int i = 0; i < 4; ++i)
                __builtin_amdgcn_global_load_lds((cg_void*)(kbase + (size_t)i*8*64),
                                                 (lds_void*)(KsW + i*512), 16, 0, 0);
        }
        // stage V tile [64 d][128 kv] (wave w: d rows w*16..+15), swizzled source
        {
            bf16* VsW = Vs + w*2048;
            #pragma unroll
            for (int i = 0; i < 4; ++i) {
                int d = w*16 + i*4 + (ln >> 4);
                __builtin_amdgcn_global_load_lds(
                    (cg_void*)(vsec + (size_t)d*1024 + kv0 + (((ln & 15) ^ (d & 7))*8)),
                    (lds_void*)(VsW + i*512), 16, 0, 0);
            }
        }
        __syncthreads();

        // QK^T: acc_s[f][c], rows q = f*16+(ln>>4)*4+j, col kv = c*16+(ln&15)
        f32x4 acc_s[2][8] = {};
        #pragma unroll
        for (int c = 0; c < 8; ++c) {
            int kvr = c*16 + (ln & 15);
            const char* krow = (const char*)Ks + kvr*128;
            short8 kf0 = *(const short8*)(krow + (((ln >> 4)*16)      ^ ((kvr & 7) << 4)));
            short8 kf1 = *(const short8*)(krow + ((64 + (ln >> 4)*16) ^ ((kvr & 7) << 4)));
            #pragma unroll
            for (int f = 0; f < 2; ++f) {
                acc_s[f][c] = __builtin_amdgcn_mfma_f32_16x16x32_bf16(qf[f][0], kf0, acc_s[f][c], 0, 0, 0);
                acc_s[f][c] = __builtin_amdgcn_mfma_f32_16x16x32_bf16(qf[f][1], kf1, acc_s[f][c], 0, 0, 0);
            }
        }

        // scale + causal mask (diag tile only) + tile row-max
        const bool diag = (kt == qt);
        f32x4 vmax[2];
        #pragma unroll
        for (int f = 0; f < 2; ++f)
            #pragma unroll
            for (int j = 0; j < 4; ++j) vmax[f][j] = -1e30f;
        #pragma unroll
        for (int f = 0; f < 2; ++f) {
            #pragma unroll
            for (int c = 0; c < 8; ++c) {
                f32x4 t = acc_s[f][c] * 0.125f;
                if (diag) {
                    int kv = kv0 + c*16 + (ln & 15);
                    int qg = q0 + w*32 + f*16 + (ln >> 4)*4;
                    #pragma unroll
                    for (int j = 0; j < 4; ++j)
                        if (kv > qg + j) t[j] = -1e30f;
                }
                acc_s[f][c] = t;
                #pragma unroll
                for (int j = 0; j < 4; ++j) vmax[f][j] = fmaxf(vmax[f][j], t[j]);
            }
            #pragma unroll
            for (int mk = 1; mk <= 8; mk <<= 1)
                #pragma unroll
                for (int j = 0; j < 4; ++j)
                    vmax[f][j] = fmaxf(vmax[f][j], __shfl_xor(vmax[f][j], mk));
        }

        // online rescale
        #pragma unroll
        for (int f = 0; f < 2; ++f) {
            f32x4 r;
            #pragma unroll
            for (int j = 0; j < 4; ++j) {
                float mn = fmaxf(m[f][j], vmax[f][j]);
                r[j] = __expf(m[f][j] - mn);
                m[f][j] = mn;
                l[f][j] *= r[j];
            }
            #pragma unroll
            for (int df = 0; df < 4; ++df)
                #pragma unroll
                for (int j = 0; j < 4; ++j) acc_o[f][df][j] *= r[j];
        }

        // P = exp(S - m), row-sum, write to per-wave LDS (bf16, swizzled)
        f32x4 rs[2] = {};
        #pragma unroll
        for (int f = 0; f < 2; ++f) {
            #pragma unroll
            for (int c = 0; c < 8; ++c) {
                #pragma unroll
                for (int j = 0; j < 4; ++j) {
                    float p = __expf(acc_s[f][c][j] - m[f][j]);
                    rs[f][j] += p;
                    int qloc = f*16 + (ln >> 4)*4 + j;
                    int kvb  = (c*16 + (ln & 15))*2;
                    *(bf16*)(PsW + qloc*256 + (kvb ^ ((qloc & 7) << 4))) = __float2bfloat16(p);
                }
            }
            #pragma unroll
            for (int mk = 1; mk <= 8; mk <<= 1)
                #pragma unroll
                for (int j = 0; j < 4; ++j)
                    rs[f][j] += __shfl_xor(rs[f][j], mk);
            #pragma unroll
            for (int j = 0; j < 4; ++j) l[f][j] += rs[f][j];
        }

        // PV: O += P @ V
        #pragma unroll
        for (int kc = 0; kc < 4; ++kc) {
            short8 pa[2];
            #pragma unroll
            for (int f = 0; f < 2; ++f) {
                int qloc = f*16 + (ln & 15);
                pa[f] = *(const short8*)(PsW + qloc*256 + ((kc*64 + (ln >> 4)*16) ^ ((qloc & 7) << 4)));
            }
            #pragma unroll
            for (int df = 0; df < 4; ++df) {
                int dl = df*16 + (ln & 15);
                short8 vfr = *(const short8*)((const char*)Vs + dl*256 + ((kc*64 + (ln >> 4)*16) ^ ((dl & 7) << 4)));
                #pragma unroll
                for (int f = 0; f < 2; ++f)
                    acc_o[f][df] = __builtin_amdgcn_mfma_f32_16x16x32_bf16(pa[f], vfr, acc_o[f][df], 0, 0, 0);
            }
        }
        __syncthreads();
    }

    // epilogue: O /= l, write ctx[t][h*64+d]
    #pragma unroll
    for (int f = 0; f < 2; ++f) {
        f32x4 inv;
        #pragma unroll
        for (int j = 0; j < 4; ++j) inv[j] = 1.0f / l[f][j];
        #pragma unroll
        for (int df = 0; df < 4; ++df) {
            #pragma unroll
            for (int j = 0; j < 4; ++j) {
                int q = q0 + w*32 + f*16 + (ln >> 4)*4 + j;
                int d = df*16 + (ln & 15);
                ctx[((size_t)b*1024 + q)*HID + h*64 + d] = __float2bfloat16(acc_o[f][df][j] * inv[j]);
            }
        }
    }
}

// ===================== launch ==============================================
extern "C" void kernel_launch(void* const* d_in, const int* in_sizes, int n_in,
                              void* d_out, int out_size, void* d_ws, size_t ws_size,
                              hipStream_t stream)
{
    const float* hidden = (const float*)d_in[0];
    const float* wq = (const float*)d_in[2];
    const float* wk = (const float*)d_in[3];
    const float* wv = (const float*)d_in[4];
    const float* wo = (const float*)d_in[5];
    const float* n1 = (const float*)d_in[6];
    const float* n2 = (const float*)d_in[7];
    const float* wg = (const float*)d_in[8];
    const float* wu = (const float*)d_in[9];
    const float* wd = (const float*)d_in[10];
    const int*  pos = (const int*)d_in[11];
    float* out = (float*)d_out;
    char* ws = (char*)d_ws;

    // workspace layout (byte offsets; total 180,355,072 B — same as round 2)
    bf16* wg_t   = (bf16*)(ws + 0);           // [8192][2048]
    bf16* wu_t   = (bf16*)(ws + 33554432);    // [8192][2048]
    bf16* wd_t   = (bf16*)(ws + 67108864);    // [2048][8192]
    bf16* wqkv_t = (bf16*)(ws + 100663296);   // [3072][2048]
    bf16* wo_t   = (bf16*)(ws + 113246208);   // [2048][2048]
    bf16* normed = (bf16*)(ws + 121634816);   // [2048][2048] (dead after qkv GEMM)
    float* qkv   = (float*)(ws + 130023424);  // [2048][3072] f32
    bf16* ctx    = (bf16*)(ws + 155189248);   // [2048][2048]
    bf16* hb     = (bf16*)(ws + 130023424);   // [2048][8192] aliases qkv+ctx (dead in FFN)
    bf16* gbh    = (bf16*)(ws + 163577856);   // [2048][4096] (FFN phase)
    // attention-phase aliases (dead regions during attn):
    bf16* Qp     = (bf16*)(ws + 121634816);   // [64][1024][64]  aliases normed
    bf16* Kp     = (bf16*)(ws + 163577856);   // [16][1024][64]  aliases gbh
    bf16* Vt     = (bf16*)(ws + 165675008);   // [16][64][1024]  aliases gbh

    // weight casts
    cast_transpose<<<dim3(32, 32), 256, 0, stream>>>(wq, wqkv_t, 2048, 2048);
    cast_transpose<<<dim3(8, 32),  256, 0, stream>>>(wk, wqkv_t + 4194304, 2048, 512);
    cast_transpose<<<dim3(8, 32),  256, 0, stream>>>(wv, wqkv_t + 5242880, 2048, 512);
    cast_transpose<<<dim3(32, 32), 256, 0, stream>>>(wo, wo_t, 2048, 2048);
    cast_transpose<<<dim3(128, 32),256, 0, stream>>>(wg, wg_t, 2048, 8192);
    cast_transpose<<<dim3(128, 32),256, 0, stream>>>(wu, wu_t, 2048, 8192);
    cast_transpose<<<dim3(32, 128),256, 0, stream>>>(wd, wd_t, 8192, 2048);

    // 1. normed = rms_norm(hidden)
    rmsnorm_kernel<<<T_TOK, 256, 0, stream>>>(hidden, n1, normed);
    // 2. qkv = normed @ [wq|wk|wv] (f32)
    mfma_gemm<0><<<dim3(QKV_N/128, T_TOK/128), 256, 0, stream>>>(
        normed, wqkv_t, qkv, nullptr, nullptr, T_TOK, QKV_N, HID, QKV_N, 0);
    // 3. RoPE+cast to head-major bf16; V transpose
    rope_cast<<<T_TOK, 256, 0, stream>>>(qkv, pos, Qp, Kp);
    vt_cast<<<dim3(16, 16), 256, 0, stream>>>(qkv, Vt);
    // 4. MFMA flash attention -> ctx (bf16)
    attn_mfma<<<dim3(8, NHEADS, 2), 256, 0, stream>>>(Qp, Kp, Vt, ctx);
    // 5. attn_out = ctx @ wo -> d_out (f32)
    mfma_gemm<0><<<dim3(HID/128, T_TOK/128), 256, 0, stream>>>(
        ctx, wo_t, out, nullptr, nullptr, T_TOK, HID, HID, HID, 0);
    // 6. normed2 = rms_norm(attn_out + hidden)
    rmsnorm_add_kernel<<<T_TOK, 256, 0, stream>>>(out, hidden, n2, normed);
    // 7-8. FFN halves: gate (silu fused), up (mul fused)
    for (int hh = 0; hh < 2; ++hh) {
        mfma_gemm<2><<<dim3(4096/128, T_TOK/128), 256, 0, stream>>>(
            normed, wg_t + (size_t)hh*4096*2048, nullptr, gbh, nullptr,
            T_TOK, 4096, HID, 4096, 0);
        mfma_gemm<3><<<dim3(4096/128, T_TOK/128), 256, 0, stream>>>(
            normed, wu_t + (size_t)hh*4096*2048, nullptr, hb + (size_t)hh*4096, gbh,
            T_TOK, 4096, HID, 8192, 4096);
    }
    // 9. d_out += hb @ wd
    mfma_gemm<1><<<dim3(HID/128, T_TOK/128), 256, 0, stream>>>(
        hb, wd_t, out, nullptr, nullptr, T_TOK, HID, FFN_DIM, HID, 0);
}

// Round 4
// 595.588 us; speedup vs baseline: 7.3244x; 1.0835x over previous
//
#include <hip/hip_runtime.h>
#include <hip/hip_bf16.h>
#include <cstddef>
#include <cstdint>

#define T_TOK   2048
#define HID     2048
#define NHEADS  32
#define NKV     8
#define HDIM    64
#define FFN_DIM 8192
#define QKV_N   3072

typedef __hip_bfloat16 bf16;
typedef __attribute__((ext_vector_type(8))) short short8;
typedef __attribute__((ext_vector_type(4))) float f32x4;
typedef __attribute__((ext_vector_type(4))) unsigned short us4;

typedef __attribute__((address_space(1))) const void cg_void;
typedef __attribute__((address_space(3))) void lds_void;

// ===================== cast + transpose: W[K][N] f32 -> Wt[N][K] bf16 ======
__global__ __launch_bounds__(256) void cast_transpose(const float* __restrict__ in,
                                                      bf16* __restrict__ out,
                                                      int K, int N)
{
    __shared__ bf16 t[64][65];
    const int n0 = blockIdx.x * 64, k0 = blockIdx.y * 64;
    const int tn = threadIdx.x & 63, tk = threadIdx.x >> 6;
    #pragma unroll
    for (int kk = tk; kk < 64; kk += 4)
        t[kk][tn] = __float2bfloat16(in[(size_t)(k0 + kk) * N + n0 + tn]);
    __syncthreads();
    #pragma unroll
    for (int nn = tk; nn < 64; nn += 4)
        out[(size_t)(n0 + nn) * K + k0 + tn] = t[tn][nn];
}

// ===================== RMSNorm (f32 in -> bf16 out) ========================
__global__ __launch_bounds__(256) void rmsnorm_kernel(const float* __restrict__ x,
                                                      const float* __restrict__ w,
                                                      bf16* __restrict__ out)
{
    __shared__ float sm[4];
    const int row = blockIdx.x, tid = threadIdx.x;
    const float4* xr = (const float4*)(x + (size_t)row * HID);
    float4 a = xr[tid], b = xr[tid + 256];
    float ss = a.x*a.x + a.y*a.y + a.z*a.z + a.w*a.w
             + b.x*b.x + b.y*b.y + b.z*b.z + b.w*b.w;
    #pragma unroll
    for (int off = 32; off; off >>= 1) ss += __shfl_down(ss, off);
    if ((tid & 63) == 0) sm[tid >> 6] = ss;
    __syncthreads();
    float sc = rsqrtf((sm[0] + sm[1] + sm[2] + sm[3]) * (1.0f / HID) + 1e-5f);
    const float4* wr = (const float4*)w;
    float4 w0 = wr[tid], w1 = wr[tid + 256];
    bf16* o = out + (size_t)row * HID;
    o[tid*4+0] = __float2bfloat16(a.x * sc * w0.x);
    o[tid*4+1] = __float2bfloat16(a.y * sc * w0.y);
    o[tid*4+2] = __float2bfloat16(a.z * sc * w0.z);
    o[tid*4+3] = __float2bfloat16(a.w * sc * w0.w);
    o[1024+tid*4+0] = __float2bfloat16(b.x * sc * w1.x);
    o[1024+tid*4+1] = __float2bfloat16(b.y * sc * w1.y);
    o[1024+tid*4+2] = __float2bfloat16(b.z * sc * w1.z);
    o[1024+tid*4+3] = __float2bfloat16(b.w * sc * w1.w);
}

// rms_norm(a + b) -> bf16
__global__ __launch_bounds__(256) void rmsnorm_add_kernel(const float* __restrict__ xa,
                                                          const float* __restrict__ xb,
                                                          const float* __restrict__ w,
                                                          bf16* __restrict__ out)
{
    __shared__ float sm[4];
    const int row = blockIdx.x, tid = threadIdx.x;
    const float4* ar = (const float4*)(xa + (size_t)row * HID);
    const float4* br = (const float4*)(xb + (size_t)row * HID);
    float4 a0 = ar[tid], a1 = ar[tid + 256];
    float4 b0 = br[tid], b1 = br[tid + 256];
    float4 s0, s1;
    s0.x = a0.x + b0.x; s0.y = a0.y + b0.y; s0.z = a0.z + b0.z; s0.w = a0.w + b0.w;
    s1.x = a1.x + b1.x; s1.y = a1.y + b1.y; s1.z = a1.z + b1.z; s1.w = a1.w + b1.w;
    float ss = s0.x*s0.x + s0.y*s0.y + s0.z*s0.z + s0.w*s0.w
             + s1.x*s1.x + s1.y*s1.y + s1.z*s1.z + s1.w*s1.w;
    #pragma unroll
    for (int off = 32; off; off >>= 1) ss += __shfl_down(ss, off);
    if ((tid & 63) == 0) sm[tid >> 6] = ss;
    __syncthreads();
    float sc = rsqrtf((sm[0] + sm[1] + sm[2] + sm[3]) * (1.0f / HID) + 1e-5f);
    const float4* wr = (const float4*)w;
    float4 w0 = wr[tid], w1 = wr[tid + 256];
    bf16* o = out + (size_t)row * HID;
    o[tid*4+0] = __float2bfloat16(s0.x * sc * w0.x);
    o[tid*4+1] = __float2bfloat16(s0.y * sc * w0.y);
    o[tid*4+2] = __float2bfloat16(s0.z * sc * w0.z);
    o[tid*4+3] = __float2bfloat16(s0.w * sc * w0.w);
    o[1024+tid*4+0] = __float2bfloat16(s1.x * sc * w1.x);
    o[1024+tid*4+1] = __float2bfloat16(s1.y * sc * w1.y);
    o[1024+tid*4+2] = __float2bfloat16(s1.z * sc * w1.z);
    o[1024+tid*4+3] = __float2bfloat16(s1.w * sc * w1.w);
}

// ===================== MFMA GEMM: C[M][N] = A[M][K] @ Bt[N][K]^T ===========
// Tile 128 x BN (BN = 64 or 128), BK=64, 4 waves (2x2); wave tile 64 x BN/2.
// T1 bijective XCD swizzle (grids are multiples of 8).
// EPI: 0 = f32 store, 1 = f32 +=, 2 = bf16 silu(acc), 3 = bf16 aux*acc
template<int BN, int EPI>
__global__ __launch_bounds__(256) void mfma_gemm(
    const bf16* __restrict__ A, const bf16* __restrict__ Bt,
    float* __restrict__ Cf, bf16* __restrict__ Cb, const bf16* __restrict__ aux,
    int M, int N, int K, int ldc, int ldaux)
{
    constexpr int NFR = BN / 32;          // B frags per wave (128->4, 64->2)
    constexpr int BCH = BN / 32;          // 8-row B chunks staged per wave
    __shared__ bf16 As[128 * 64];
    __shared__ bf16 Bs[BN * 64];
    const int tid = threadIdx.x;
    const int wv = tid >> 6, ln = tid & 63;
    const int wr = wv >> 1, wc = wv & 1;

    // XCD-aware swizzle: contiguous work chunk per XCD
    const int nwg = gridDim.x * gridDim.y;
    int orig = blockIdx.y * gridDim.x + blockIdx.x;
    int wg = (orig & 7) * (nwg >> 3) + (orig >> 3);
    const int bx = wg % gridDim.x, by = wg / gridDim.x;
    const size_t m0 = (size_t)by * 128;
    const size_t n0 = (size_t)bx * BN;

    const int lrow = ln >> 3;
    const int lk   = (ln & 7) ^ lrow;     // inverse-swizzled source k-chunk

    f32x4 acc[4][NFR] = {};

    const bf16* Abase = A  + (m0 + (size_t)(wv*4)*8 + lrow) * K + lk*8;
    const bf16* Bbase = Bt + (n0 + (size_t)(wv*BCH)*8 + lrow) * K + lk*8;
    bf16* AsW = As + wv*4*512;
    bf16* BsW = Bs + wv*BCH*512;

    for (int kt = 0; kt < K; kt += 64) {
        #pragma unroll
        for (int i = 0; i < 4; ++i)
            __builtin_amdgcn_global_load_lds((cg_void*)(Abase + (size_t)i*8*K + kt),
                                             (lds_void*)(AsW + i*512), 16, 0, 0);
        #pragma unroll
        for (int i = 0; i < BCH; ++i)
            __builtin_amdgcn_global_load_lds((cg_void*)(Bbase + (size_t)i*8*K + kt),
                                             (lds_void*)(BsW + i*512), 16, 0, 0);
        __syncthreads();
        #pragma unroll
        for (int ks = 0; ks < 2; ++ks) {
            short8 af[4], bfg[NFR];
            const int kbyte = ks*64 + (ln >> 4)*16;
            #pragma unroll
            for (int m = 0; m < 4; ++m) {
                int row = wr*64 + m*16 + (ln & 15);
                af[m] = *(const short8*)((const char*)As + row*128 + (kbyte ^ ((row & 7) << 4)));
            }
            #pragma unroll
            for (int n = 0; n < NFR; ++n) {
                int row = wc*(BN/2) + n*16 + (ln & 15);
                bfg[n] = *(const short8*)((const char*)Bs + row*128 + (kbyte ^ ((row & 7) << 4)));
            }
            #pragma unroll
            for (int m = 0; m < 4; ++m)
                #pragma unroll
                for (int n = 0; n < NFR; ++n)
                    acc[m][n] = __builtin_amdgcn_mfma_f32_16x16x32_bf16(af[m], bfg[n], acc[m][n], 0, 0, 0);
        }
        __syncthreads();
    }

    // C/D layout: col = lane&15, row = (lane>>4)*4 + reg
    const int cj = ln & 15, rj = ln >> 4;
    #pragma unroll
    for (int m = 0; m < 4; ++m) {
        #pragma unroll
        for (int j = 0; j < 4; ++j) {
            size_t row = m0 + wr*64 + m*16 + rj*4 + j;
            #pragma unroll
            for (int n = 0; n < NFR; ++n) {
                int col = (int)n0 + wc*(BN/2) + n*16 + cj;
                float v = acc[m][n][j];
                size_t off = row * (size_t)ldc + col;
                if constexpr (EPI == 0) {
                    Cf[off] = v;
                } else if constexpr (EPI == 1) {
                    Cf[off] += v;
                } else if constexpr (EPI == 2) {
                    Cb[off] = __float2bfloat16(v / (1.0f + __expf(-v)));
                } else {
                    float g = __bfloat162float(aux[row * (size_t)ldaux + col]);
                    Cb[off] = __float2bfloat16(g * v);
                }
            }
        }
    }
}

// ===================== RoPE + cast: qkv f32 -> Qp/Kp bf16 (head-major) =====
// Qp: [2][32][1024][64], Kp: [2][8][1024][64]
__global__ __launch_bounds__(256) void rope_cast(const float* __restrict__ qkv,
                                                 const int* __restrict__ pos_ids,
                                                 bf16* __restrict__ Qp,
                                                 bf16* __restrict__ Kp)
{
    const int t = blockIdx.x, tid = threadIdx.x;
    const int b = t >> 10, s = t & 1023;
    const float pos = (float)pos_ids[t];
    const float* row = qkv + (size_t)t * QKV_N;

    {
        int idx = tid * 4;
        int hq = idx >> 5, j = idx & 31;
        float xa[4], xb[4];
        *(float4*)xa = *(const float4*)(row + hq*64 + j);
        *(float4*)xb = *(const float4*)(row + hq*64 + j + 32);
        us4 o1, o2;
        #pragma unroll
        for (int jj = 0; jj < 4; ++jj) {
            float inv = exp2f(-(float)(j + jj) * 0.5916115177913804f);
            float ang = pos * inv, c, sn;
            sincosf(ang, &sn, &c);
            o1[jj] = __bfloat16_as_ushort(__float2bfloat16(xa[jj]*c - xb[jj]*sn));
            o2[jj] = __bfloat16_as_ushort(__float2bfloat16(xb[jj]*c + xa[jj]*sn));
        }
        bf16* qd = Qp + ((size_t)(b*32 + hq)*1024 + s)*64;
        *(us4*)(qd + j)      = o1;
        *(us4*)(qd + j + 32) = o2;
    }
    {
        int hk = tid >> 5, j = tid & 31;
        float a = row[2048 + hk*64 + j];
        float bb = row[2048 + hk*64 + j + 32];
        float inv = exp2f(-(float)j * 0.5916115177913804f);
        float ang = pos * inv, c, sn;
        sincosf(ang, &sn, &c);
        bf16* kd = Kp + ((size_t)(b*8 + hk)*1024 + s)*64;
        kd[j]      = __float2bfloat16(a*c - bb*sn);
        kd[j + 32] = __float2bfloat16(bb*c + a*sn);
    }
}

// ===================== V transpose+cast: qkv f32 -> Vt[16][64][1024] bf16 ==
__global__ __launch_bounds__(256) void vt_cast(const float* __restrict__ qkv,
                                               bf16* __restrict__ Vt)
{
    __shared__ bf16 tile[64][64];
    const int s0 = blockIdx.x * 64;
    const int sec = blockIdx.y;                 // b*8 + hk
    const int b = sec >> 3, hk = sec & 7;
    const int tid = threadIdx.x;
    const float* base = qkv + ((size_t)(b*1024 + s0)) * QKV_N + 2560 + hk*64;
    const int srow = tid >> 2, d0 = (tid & 3) * 16;
    #pragma unroll
    for (int q = 0; q < 4; ++q) {
        float va[4];
        *(float4*)va = *(const float4*)(base + (size_t)srow * QKV_N + d0 + q*4);
        #pragma unroll
        for (int cc = 0; cc < 4; ++cc)
            tile[d0 + q*4 + cc][srow] = __float2bfloat16(va[cc]);
    }
    __syncthreads();
    const int dr = tid >> 2, sc = (tid & 3) * 16;
    bf16* od = Vt + ((size_t)sec*64 + dr)*1024 + s0 + sc;
    *(short8*)od       = *(const short8*)&tile[dr][sc];
    *(short8*)(od + 8) = *(const short8*)&tile[dr][sc + 8];
}

// ===================== MFMA flash attention (bf16, causal, GQA) ============
__global__ __launch_bounds__(256) void attn_mfma(const bf16* __restrict__ Qp,
                                                 const bf16* __restrict__ Kp,
                                                 const bf16* __restrict__ Vt,
                                                 bf16* __restrict__ ctx)
{
    __shared__ bf16 Ks[128 * 64];
    __shared__ bf16 Vs[64 * 128];
    __shared__ bf16 Ps[4 * 32 * 128];
    const int tid = threadIdx.x;
    const int w = tid >> 6, ln = tid & 63;
    const int qt = blockIdx.x, h = blockIdx.y, b = blockIdx.z;
    const int hk = h >> 2;
    const int q0 = qt * 128;

    const bf16* qsec = Qp + ((size_t)(b*32 + h)*1024 + q0 + w*32)*64;
    const bf16* ksec = Kp + ((size_t)(b*8 + hk)*1024)*64;
    const bf16* vsec = Vt + ((size_t)(b*8 + hk))*64*1024;

    short8 qf[2][2];
    #pragma unroll
    for (int f = 0; f < 2; ++f)
        #pragma unroll
        for (int kc = 0; kc < 2; ++kc)
            qf[f][kc] = *(const short8*)(qsec + (size_t)(f*16 + (ln & 15))*64 + kc*32 + (ln >> 4)*8);

    f32x4 acc_o[2][4] = {};
    f32x4 m[2], l[2];
    #pragma unroll
    for (int f = 0; f < 2; ++f)
        #pragma unroll
        for (int j = 0; j < 4; ++j) { m[f][j] = -1e30f; l[f][j] = 0.0f; }

    const int lrow = ln >> 3;
    const int lkk  = (ln & 7) ^ lrow;
    char* PsW = (char*)Ps + w * 8192;

    const int ntiles = qt + 1;
    for (int kt = 0; kt < ntiles; ++kt) {
        const int kv0 = kt * 128;
        {
            const bf16* kbase = ksec + (size_t)(kv0 + w*32 + lrow)*64 + lkk*8;
            bf16* KsW = Ks + w*2048;
            #pragma unroll
            for (int i = 0; i < 4; ++i)
                __builtin_amdgcn_global_load_lds((cg_void*)(kbase + (size_t)i*8*64),
                                                 (lds_void*)(KsW + i*512), 16, 0, 0);
        }
        {
            bf16* VsW = Vs + w*2048;
            #pragma unroll
            for (int i = 0; i < 4; ++i) {
                int d = w*16 + i*4 + (ln >> 4);
                __builtin_amdgcn_global_load_lds(
                    (cg_void*)(vsec + (size_t)d*1024 + kv0 + (((ln & 15) ^ (d & 7))*8)),
                    (lds_void*)(VsW + i*512), 16, 0, 0);
            }
        }
        __syncthreads();

        f32x4 acc_s[2][8] = {};
        #pragma unroll
        for (int c = 0; c < 8; ++c) {
            int kvr = c*16 + (ln & 15);
            const char* krow = (const char*)Ks + kvr*128;
            short8 kf0 = *(const short8*)(krow + (((ln >> 4)*16)      ^ ((kvr & 7) << 4)));
            short8 kf1 = *(const short8*)(krow + ((64 + (ln >> 4)*16) ^ ((kvr & 7) << 4)));
            #pragma unroll
            for (int f = 0; f < 2; ++f) {
                acc_s[f][c] = __builtin_amdgcn_mfma_f32_16x16x32_bf16(qf[f][0], kf0, acc_s[f][c], 0, 0, 0);
                acc_s[f][c] = __builtin_amdgcn_mfma_f32_16x16x32_bf16(qf[f][1], kf1, acc_s[f][c], 0, 0, 0);
            }
        }

        const bool diag = (kt == qt);
        f32x4 vmax[2];
        #pragma unroll
        for (int f = 0; f < 2; ++f)
            #pragma unroll
            for (int j = 0; j < 4; ++j) vmax[f][j] = -1e30f;
        #pragma unroll
        for (int f = 0; f < 2; ++f) {
            #pragma unroll
            for (int c = 0; c < 8; ++c) {
                f32x4 t = acc_s[f][c] * 0.125f;
                if (diag) {
                    int kv = kv0 + c*16 + (ln & 15);
                    int qg = q0 + w*32 + f*16 + (ln >> 4)*4;
                    #pragma unroll
                    for (int j = 0; j < 4; ++j)
                        if (kv > qg + j) t[j] = -1e30f;
                }
                acc_s[f][c] = t;
                #pragma unroll
                for (int j = 0; j < 4; ++j) vmax[f][j] = fmaxf(vmax[f][j], t[j]);
            }
            #pragma unroll
            for (int mk = 1; mk <= 8; mk <<= 1)
                #pragma unroll
                for (int j = 0; j < 4; ++j)
                    vmax[f][j] = fmaxf(vmax[f][j], __shfl_xor(vmax[f][j], mk));
        }

        #pragma unroll
        for (int f = 0; f < 2; ++f) {
            f32x4 r;
            #pragma unroll
            for (int j = 0; j < 4; ++j) {
                float mn = fmaxf(m[f][j], vmax[f][j]);
                r[j] = __expf(m[f][j] - mn);
                m[f][j] = mn;
                l[f][j] *= r[j];
            }
            #pragma unroll
            for (int df = 0; df < 4; ++df)
                #pragma unroll
                for (int j = 0; j < 4; ++j) acc_o[f][df][j] *= r[j];
        }

        f32x4 rs[2] = {};
        #pragma unroll
        for (int f = 0; f < 2; ++f) {
            #pragma unroll
            for (int c = 0; c < 8; ++c) {
                #pragma unroll
                for (int j = 0; j < 4; ++j) {
                    float p = __expf(acc_s[f][c][j] - m[f][j]);
                    rs[f][j] += p;
                    int qloc = f*16 + (ln >> 4)*4 + j;
                    int kvb  = (c*16 + (ln & 15))*2;
                    *(bf16*)(PsW + qloc*256 + (kvb ^ ((qloc & 7) << 4))) = __float2bfloat16(p);
                }
            }
            #pragma unroll
            for (int mk = 1; mk <= 8; mk <<= 1)
                #pragma unroll
                for (int j = 0; j < 4; ++j)
                    rs[f][j] += __shfl_xor(rs[f][j], mk);
            #pragma unroll
            for (int j = 0; j < 4; ++j) l[f][j] += rs[f][j];
        }

        #pragma unroll
        for (int kc = 0; kc < 4; ++kc) {
            short8 pa[2];
            #pragma unroll
            for (int f = 0; f < 2; ++f) {
                int qloc = f*16 + (ln & 15);
                pa[f] = *(const short8*)(PsW + qloc*256 + ((kc*64 + (ln >> 4)*16) ^ ((qloc & 7) << 4)));
            }
            #pragma unroll
            for (int df = 0; df < 4; ++df) {
                int dl = df*16 + (ln & 15);
                short8 vfr = *(const short8*)((const char*)Vs + dl*256 + ((kc*64 + (ln >> 4)*16) ^ ((dl & 7) << 4)));
                #pragma unroll
                for (int f = 0; f < 2; ++f)
                    acc_o[f][df] = __builtin_amdgcn_mfma_f32_16x16x32_bf16(pa[f], vfr, acc_o[f][df], 0, 0, 0);
            }
        }
        __syncthreads();
    }

    #pragma unroll
    for (int f = 0; f < 2; ++f) {
        f32x4 inv;
        #pragma unroll
        for (int j = 0; j < 4; ++j) inv[j] = 1.0f / l[f][j];
        #pragma unroll
        for (int df = 0; df < 4; ++df) {
            #pragma unroll
            for (int j = 0; j < 4; ++j) {
                int q = q0 + w*32 + f*16 + (ln >> 4)*4 + j;
                int d = df*16 + (ln & 15);
                ctx[((size_t)b*1024 + q)*HID + h*64 + d] = __float2bfloat16(acc_o[f][df][j] * inv[j]);
            }
        }
    }
}

// ===================== launch ==============================================
extern "C" void kernel_launch(void* const* d_in, const int* in_sizes, int n_in,
                              void* d_out, int out_size, void* d_ws, size_t ws_size,
                              hipStream_t stream)
{
    const float* hidden = (const float*)d_in[0];
    const float* wq = (const float*)d_in[2];
    const float* wk = (const float*)d_in[3];
    const float* wv = (const float*)d_in[4];
    const float* wo = (const float*)d_in[5];
    const float* n1 = (const float*)d_in[6];
    const float* n2 = (const float*)d_in[7];
    const float* wg = (const float*)d_in[8];
    const float* wu = (const float*)d_in[9];
    const float* wd = (const float*)d_in[10];
    const int*  pos = (const int*)d_in[11];
    float* out = (float*)d_out;
    char* ws = (char*)d_ws;

    // workspace layout (byte offsets; total 180,355,072 B)
    bf16* wg_t   = (bf16*)(ws + 0);           // [8192][2048]
    bf16* wu_t   = (bf16*)(ws + 33554432);    // [8192][2048]
    bf16* wd_t   = (bf16*)(ws + 67108864);    // [2048][8192]
    bf16* wqkv_t = (bf16*)(ws + 100663296);   // [3072][2048]
    bf16* wo_t   = (bf16*)(ws + 113246208);   // [2048][2048]
    bf16* normed = (bf16*)(ws + 121634816);   // [2048][2048]
    float* qkv   = (float*)(ws + 130023424);  // [2048][3072] f32
    bf16* ctx    = (bf16*)(ws + 155189248);   // [2048][2048]
    bf16* hb     = (bf16*)(ws + 130023424);   // [2048][8192] aliases qkv+ctx
    bf16* gbh    = (bf16*)(ws + 163577856);   // [2048][4096]
    bf16* Qp     = (bf16*)(ws + 121634816);   // aliases normed (dead during attn)
    bf16* Kp     = (bf16*)(ws + 163577856);   // aliases gbh
    bf16* Vt     = (bf16*)(ws + 165675008);   // aliases gbh

    // weight casts
    cast_transpose<<<dim3(32, 32), 256, 0, stream>>>(wq, wqkv_t, 2048, 2048);
    cast_transpose<<<dim3(8, 32),  256, 0, stream>>>(wk, wqkv_t + 4194304, 2048, 512);
    cast_transpose<<<dim3(8, 32),  256, 0, stream>>>(wv, wqkv_t + 5242880, 2048, 512);
    cast_transpose<<<dim3(32, 32), 256, 0, stream>>>(wo, wo_t, 2048, 2048);
    cast_transpose<<<dim3(128, 32),256, 0, stream>>>(wg, wg_t, 2048, 8192);
    cast_transpose<<<dim3(128, 32),256, 0, stream>>>(wu, wu_t, 2048, 8192);
    cast_transpose<<<dim3(32, 128),256, 0, stream>>>(wd, wd_t, 8192, 2048);

    // 1. normed = rms_norm(hidden)
    rmsnorm_kernel<<<T_TOK, 256, 0, stream>>>(hidden, n1, normed);
    // 2. qkv = normed @ [wq|wk|wv] (f32)   grid 48x16 = 768 wg (3/CU)
    mfma_gemm<64,0><<<dim3(QKV_N/64, T_TOK/128), 256, 0, stream>>>(
        normed, wqkv_t, qkv, nullptr, nullptr, T_TOK, QKV_N, HID, QKV_N, 0);
    // 3. RoPE+cast; V transpose
    rope_cast<<<T_TOK, 256, 0, stream>>>(qkv, pos, Qp, Kp);
    vt_cast<<<dim3(16, 16), 256, 0, stream>>>(qkv, Vt);
    // 4. MFMA flash attention -> ctx (bf16)
    attn_mfma<<<dim3(8, NHEADS, 2), 256, 0, stream>>>(Qp, Kp, Vt, ctx);
    // 5. attn_out = ctx @ wo -> d_out (f32)   grid 32x16 = 512 wg (2/CU)
    mfma_gemm<64,0><<<dim3(HID/64, T_TOK/128), 256, 0, stream>>>(
        ctx, wo_t, out, nullptr, nullptr, T_TOK, HID, HID, HID, 0);
    // 6. normed2 = rms_norm(attn_out + hidden)
    rmsnorm_add_kernel<<<T_TOK, 256, 0, stream>>>(out, hidden, n2, normed);
    // 7-8. FFN halves: gate (silu fused), up (mul fused)   grid 64x16 = 1024 wg
    for (int hh = 0; hh < 2; ++hh) {
        mfma_gemm<64,2><<<dim3(4096/64, T_TOK/128), 256, 0, stream>>>(
            normed, wg_t + (size_t)hh*4096*2048, nullptr, gbh, nullptr,
            T_TOK, 4096, HID, 4096, 0);
        mfma_gemm<64,3><<<dim3(4096/64, T_TOK/128), 256, 0, stream>>>(
            normed, wu_t + (size_t)hh*4096*2048, nullptr, hb + (size_t)hh*4096, gbh,
            T_TOK, 4096, HID, 8192, 4096);
    }
    // 9. d_out += hb @ wd   grid 32x16 = 512 wg (2/CU)
    mfma_gemm<64,1><<<dim3(HID/64, T_TOK/128), 256, 0, stream>>>(
        hb, wd_t, out, nullptr, nullptr, T_TOK, HID, FFN_DIM, HID, 0);
}

// Round 5
// 532.399 us; speedup vs baseline: 8.1937x; 1.1187x over previous
//
#include <hip/hip_runtime.h>
#include <hip/hip_bf16.h>
#include <cstddef>
#include <cstdint>

#define T_TOK   2048
#define HID     2048
#define NHEADS  32
#define NKV     8
#define HDIM    64
#define FFN_DIM 8192
#define QKV_N   3072

typedef __hip_bfloat16 bf16;
typedef __attribute__((ext_vector_type(8))) short short8;
typedef __attribute__((ext_vector_type(4))) float f32x4;
typedef __attribute__((ext_vector_type(4))) unsigned short us4;

typedef __attribute__((address_space(1))) const void cg_void;
typedef __attribute__((address_space(3))) void lds_void;

// ===================== cast + transpose: W[K][N] f32 -> Wt[N][K] bf16 ======
__global__ __launch_bounds__(256) void cast_transpose(const float* __restrict__ in,
                                                      bf16* __restrict__ out,
                                                      int K, int N)
{
    __shared__ bf16 t[64][65];
    const int n0 = blockIdx.x * 64, k0 = blockIdx.y * 64;
    const int tn = threadIdx.x & 63, tk = threadIdx.x >> 6;
    #pragma unroll
    for (int kk = tk; kk < 64; kk += 4)
        t[kk][tn] = __float2bfloat16(in[(size_t)(k0 + kk) * N + n0 + tn]);
    __syncthreads();
    #pragma unroll
    for (int nn = tk; nn < 64; nn += 4)
        out[(size_t)(n0 + nn) * K + k0 + tn] = t[tn][nn];
}

// interleaved variant for gate/up fusion: col n -> row (n/32)*64 + is_up*32 + n%32
__global__ __launch_bounds__(256) void cast_ilv(const float* __restrict__ in,
                                                bf16* __restrict__ out,
                                                int N, int is_up)
{
    __shared__ bf16 t[64][65];
    const int n0 = blockIdx.x * 64, k0 = blockIdx.y * 64;
    const int tn = threadIdx.x & 63, tk = threadIdx.x >> 6;
    #pragma unroll
    for (int kk = tk; kk < 64; kk += 4)
        t[kk][tn] = __float2bfloat16(in[(size_t)(k0 + kk) * N + n0 + tn]);
    __syncthreads();
    #pragma unroll
    for (int nn = tk; nn < 64; nn += 4) {
        int n = n0 + nn;
        int r = ((n >> 5) << 6) + (is_up << 5) + (n & 31);
        out[(size_t)r * HID + k0 + tn] = t[tn][nn];
    }
}

// ===================== RMSNorm (f32 in -> bf16 out) ========================
__global__ __launch_bounds__(256) void rmsnorm_kernel(const float* __restrict__ x,
                                                      const float* __restrict__ w,
                                                      bf16* __restrict__ out)
{
    __shared__ float sm[4];
    const int row = blockIdx.x, tid = threadIdx.x;
    const float4* xr = (const float4*)(x + (size_t)row * HID);
    float4 a = xr[tid], b = xr[tid + 256];
    float ss = a.x*a.x + a.y*a.y + a.z*a.z + a.w*a.w
             + b.x*b.x + b.y*b.y + b.z*b.z + b.w*b.w;
    #pragma unroll
    for (int off = 32; off; off >>= 1) ss += __shfl_down(ss, off);
    if ((tid & 63) == 0) sm[tid >> 6] = ss;
    __syncthreads();
    float sc = rsqrtf((sm[0] + sm[1] + sm[2] + sm[3]) * (1.0f / HID) + 1e-5f);
    const float4* wr = (const float4*)w;
    float4 w0 = wr[tid], w1 = wr[tid + 256];
    bf16* o = out + (size_t)row * HID;
    o[tid*4+0] = __float2bfloat16(a.x * sc * w0.x);
    o[tid*4+1] = __float2bfloat16(a.y * sc * w0.y);
    o[tid*4+2] = __float2bfloat16(a.z * sc * w0.z);
    o[tid*4+3] = __float2bfloat16(a.w * sc * w0.w);
    o[1024+tid*4+0] = __float2bfloat16(b.x * sc * w1.x);
    o[1024+tid*4+1] = __float2bfloat16(b.y * sc * w1.y);
    o[1024+tid*4+2] = __float2bfloat16(b.z * sc * w1.z);
    o[1024+tid*4+3] = __float2bfloat16(b.w * sc * w1.w);
}

// rms_norm(a + b) -> bf16
__global__ __launch_bounds__(256) void rmsnorm_add_kernel(const float* __restrict__ xa,
                                                          const float* __restrict__ xb,
                                                          const float* __restrict__ w,
                                                          bf16* __restrict__ out)
{
    __shared__ float sm[4];
    const int row = blockIdx.x, tid = threadIdx.x;
    const float4* ar = (const float4*)(xa + (size_t)row * HID);
    const float4* br = (const float4*)(xb + (size_t)row * HID);
    float4 a0 = ar[tid], a1 = ar[tid + 256];
    float4 b0 = br[tid], b1 = br[tid + 256];
    float4 s0, s1;
    s0.x = a0.x + b0.x; s0.y = a0.y + b0.y; s0.z = a0.z + b0.z; s0.w = a0.w + b0.w;
    s1.x = a1.x + b1.x; s1.y = a1.y + b1.y; s1.z = a1.z + b1.z; s1.w = a1.w + b1.w;
    float ss = s0.x*s0.x + s0.y*s0.y + s0.z*s0.z + s0.w*s0.w
             + s1.x*s1.x + s1.y*s1.y + s1.z*s1.z + s1.w*s1.w;
    #pragma unroll
    for (int off = 32; off; off >>= 1) ss += __shfl_down(ss, off);
    if ((tid & 63) == 0) sm[tid >> 6] = ss;
    __syncthreads();
    float sc = rsqrtf((sm[0] + sm[1] + sm[2] + sm[3]) * (1.0f / HID) + 1e-5f);
    const float4* wr = (const float4*)w;
    float4 w0 = wr[tid], w1 = wr[tid + 256];
    bf16* o = out + (size_t)row * HID;
    o[tid*4+0] = __float2bfloat16(s0.x * sc * w0.x);
    o[tid*4+1] = __float2bfloat16(s0.y * sc * w0.y);
    o[tid*4+2] = __float2bfloat16(s0.z * sc * w0.z);
    o[tid*4+3] = __float2bfloat16(s0.w * sc * w0.w);
    o[1024+tid*4+0] = __float2bfloat16(s1.x * sc * w1.x);
    o[1024+tid*4+1] = __float2bfloat16(s1.y * sc * w1.y);
    o[1024+tid*4+2] = __float2bfloat16(s1.z * sc * w1.z);
    o[1024+tid*4+3] = __float2bfloat16(s1.w * sc * w1.w);
}

// ===================== shared MFMA GEMM body ===============================
// C[M][N] = A[M][K] @ Bt[N][K]^T, tile 128 x BN, BK=64, 4 waves (2x2).
// EPI: 0 = f32 store, 4 = gateup pair silu(g)*u -> bf16, 5 = f32 atomicAdd
template<int BN, int EPI>
__device__ __forceinline__ void gemm_body(
    const bf16* __restrict__ A, const bf16* __restrict__ Bt,
    float* __restrict__ Cf, bf16* __restrict__ Cb,
    int lda, int kbeg, int klen, int ldc, int bx, int by)
{
    constexpr int NFR = BN / 32;          // B frags per wave
    constexpr int BCH = BN / 32;          // 8-row B chunks staged per wave
    __shared__ bf16 As[128 * 64];
    __shared__ bf16 Bs[BN * 64];
    const int tid = threadIdx.x;
    const int wv = tid >> 6, ln = tid & 63;
    const int wr = wv >> 1, wc = wv & 1;
    const size_t m0 = (size_t)by * 128;
    const size_t n0 = (size_t)bx * BN;

    const int lrow = ln >> 3;
    const int lk   = (ln & 7) ^ lrow;     // inverse-swizzled source k-chunk

    f32x4 acc[4][NFR] = {};

    const bf16* Abase = A  + (m0 + (size_t)wv*32 + lrow) * lda + kbeg + lk*8;
    const bf16* Bbase = Bt + (n0 + (size_t)wv*BCH*8 + lrow) * lda + kbeg + lk*8;
    bf16* AsW = As + wv*4*512;
    bf16* BsW = Bs + wv*BCH*512;

    for (int kt = 0; kt < klen; kt += 64) {
        #pragma unroll
        for (int i = 0; i < 4; ++i)
            __builtin_amdgcn_global_load_lds((cg_void*)(Abase + (size_t)i*8*lda + kt),
                                             (lds_void*)(AsW + i*512), 16, 0, 0);
        #pragma unroll
        for (int i = 0; i < BCH; ++i)
            __builtin_amdgcn_global_load_lds((cg_void*)(Bbase + (size_t)i*8*lda + kt),
                                             (lds_void*)(BsW + i*512), 16, 0, 0);
        __syncthreads();
        #pragma unroll
        for (int ks = 0; ks < 2; ++ks) {
            short8 af[4], bfg[NFR];
            const int kbyte = ks*64 + (ln >> 4)*16;
            #pragma unroll
            for (int m = 0; m < 4; ++m) {
                int row = wr*64 + m*16 + (ln & 15);
                af[m] = *(const short8*)((const char*)As + row*128 + (kbyte ^ ((row & 7) << 4)));
            }
            #pragma unroll
            for (int n = 0; n < NFR; ++n) {
                int row = wc*(BN/2) + n*16 + (ln & 15);
                bfg[n] = *(const short8*)((const char*)Bs + row*128 + (kbyte ^ ((row & 7) << 4)));
            }
            #pragma unroll
            for (int m = 0; m < 4; ++m)
                #pragma unroll
                for (int n = 0; n < NFR; ++n)
                    acc[m][n] = __builtin_amdgcn_mfma_f32_16x16x32_bf16(af[m], bfg[n], acc[m][n], 0, 0, 0);
        }
        __syncthreads();
    }

    // C/D layout: col = lane&15, row = (lane>>4)*4 + reg
    const int cj = ln & 15, rj = ln >> 4;
    if constexpr (EPI == 4) {
        // gateup: frag n in {0,1} = gate cols, n+2 = matching up cols
        #pragma unroll
        for (int m = 0; m < 4; ++m) {
            #pragma unroll
            for (int j = 0; j < 4; ++j) {
                size_t row = m0 + wr*64 + m*16 + rj*4 + j;
                #pragma unroll
                for (int n = 0; n < 2; ++n) {
                    int col = ((int)(n0 >> 6) + wc) * 32 + n*16 + cj;
                    float g = acc[m][n][j];
                    float u = acc[m][n+2][j];
                    Cb[row * (size_t)ldc + col] =
                        __float2bfloat16(g / (1.0f + __expf(-g)) * u);
                }
            }
        }
    } else {
        #pragma unroll
        for (int m = 0; m < 4; ++m) {
            #pragma unroll
            for (int j = 0; j < 4; ++j) {
                size_t row = m0 + wr*64 + m*16 + rj*4 + j;
                #pragma unroll
                for (int n = 0; n < NFR; ++n) {
                    int col = (int)n0 + wc*(BN/2) + n*16 + cj;
                    float v = acc[m][n][j];
                    size_t off = row * (size_t)ldc + col;
                    if constexpr (EPI == 0) Cf[off] = v;
                    else if constexpr (EPI == 5) unsafeAtomicAdd(&Cf[off], v);
                }
            }
        }
    }
}

// wrappers with distinct names (profiling attribution) + XCD swizzle
__device__ __forceinline__ void swz(int& bx, int& by) {
    const int nwg = gridDim.x * gridDim.y;
    int orig = blockIdx.y * gridDim.x + blockIdx.x;
    int wg = (orig & 7) * (nwg >> 3) + (orig >> 3);
    bx = wg % gridDim.x; by = wg / gridDim.x;
}

__global__ __launch_bounds__(256) void g_qkv(const bf16* __restrict__ A,
                                             const bf16* __restrict__ Bt,
                                             float* __restrict__ C) {
    int bx, by; swz(bx, by);
    gemm_body<64,0>(A, Bt, C, nullptr, HID, 0, HID, QKV_N, bx, by);
}
__global__ __launch_bounds__(256) void g_wo(const bf16* __restrict__ A,
                                            const bf16* __restrict__ Bt,
                                            float* __restrict__ C) {
    int bx, by; swz(bx, by);
    gemm_body<64,0>(A, Bt, C, nullptr, HID, 0, HID, HID, bx, by);
}
__global__ __launch_bounds__(256) void g_gateup(const bf16* __restrict__ A,
                                                const bf16* __restrict__ Bt,
                                                bf16* __restrict__ C) {
    int bx, by; swz(bx, by);
    gemm_body<128,4>(A, Bt, nullptr, C, HID, 0, HID, FFN_DIM, bx, by);
}
__global__ __launch_bounds__(256) void g_down(const bf16* __restrict__ A,
                                              const bf16* __restrict__ Bt,
                                              float* __restrict__ C) {
    int bx, by; swz(bx, by);
    gemm_body<64,5>(A, Bt, C, nullptr, FFN_DIM, blockIdx.z * 4096, 4096, HID, bx, by);
}

// ===================== RoPE + cast: qkv f32 -> Qp/Kp bf16 (head-major) =====
__global__ __launch_bounds__(256) void rope_cast(const float* __restrict__ qkv,
                                                 const int* __restrict__ pos_ids,
                                                 bf16* __restrict__ Qp,
                                                 bf16* __restrict__ Kp)
{
    const int t = blockIdx.x, tid = threadIdx.x;
    const int b = t >> 10, s = t & 1023;
    const float pos = (float)pos_ids[t];
    const float* row = qkv + (size_t)t * QKV_N;

    {
        int idx = tid * 4;
        int hq = idx >> 5, j = idx & 31;
        float xa[4], xb[4];
        *(float4*)xa = *(const float4*)(row + hq*64 + j);
        *(float4*)xb = *(const float4*)(row + hq*64 + j + 32);
        us4 o1, o2;
        #pragma unroll
        for (int jj = 0; jj < 4; ++jj) {
            float inv = exp2f(-(float)(j + jj) * 0.5916115177913804f);
            float ang = pos * inv, c, sn;
            sincosf(ang, &sn, &c);
            o1[jj] = __bfloat16_as_ushort(__float2bfloat16(xa[jj]*c - xb[jj]*sn));
            o2[jj] = __bfloat16_as_ushort(__float2bfloat16(xb[jj]*c + xa[jj]*sn));
        }
        bf16* qd = Qp + ((size_t)(b*32 + hq)*1024 + s)*64;
        *(us4*)(qd + j)      = o1;
        *(us4*)(qd + j + 32) = o2;
    }
    {
        int hk = tid >> 5, j = tid & 31;
        float a = row[2048 + hk*64 + j];
        float bb = row[2048 + hk*64 + j + 32];
        float inv = exp2f(-(float)j * 0.5916115177913804f);
        float ang = pos * inv, c, sn;
        sincosf(ang, &sn, &c);
        bf16* kd = Kp + ((size_t)(b*8 + hk)*1024 + s)*64;
        kd[j]      = __float2bfloat16(a*c - bb*sn);
        kd[j + 32] = __float2bfloat16(bb*c + a*sn);
    }
}

// ===================== V transpose+cast: qkv f32 -> Vt[16][64][1024] bf16 ==
__global__ __launch_bounds__(256) void vt_cast(const float* __restrict__ qkv,
                                               bf16* __restrict__ Vt)
{
    __shared__ bf16 tile[64][64];
    const int s0 = blockIdx.x * 64;
    const int sec = blockIdx.y;                 // b*8 + hk
    const int b = sec >> 3, hk = sec & 7;
    const int tid = threadIdx.x;
    const float* base = qkv + ((size_t)(b*1024 + s0)) * QKV_N + 2560 + hk*64;
    const int srow = tid >> 2, d0 = (tid & 3) * 16;
    #pragma unroll
    for (int q = 0; q < 4; ++q) {
        float va[4];
        *(float4*)va = *(const float4*)(base + (size_t)srow * QKV_N + d0 + q*4);
        #pragma unroll
        for (int cc = 0; cc < 4; ++cc)
            tile[d0 + q*4 + cc][srow] = __float2bfloat16(va[cc]);
    }
    __syncthreads();
    const int dr = tid >> 2, sc = (tid & 3) * 16;
    bf16* od = Vt + ((size_t)sec*64 + dr)*1024 + s0 + sc;
    *(short8*)od       = *(const short8*)&tile[dr][sc];
    *(short8*)(od + 8) = *(const short8*)&tile[dr][sc + 8];
}

// ===================== MFMA flash attention (bf16, causal, GQA) ============
__global__ __launch_bounds__(256) void attn_mfma(const bf16* __restrict__ Qp,
                                                 const bf16* __restrict__ Kp,
                                                 const bf16* __restrict__ Vt,
                                                 bf16* __restrict__ ctx)
{
    __shared__ bf16 Ks[128 * 64];
    __shared__ bf16 Vs[64 * 128];
    __shared__ bf16 Ps[4 * 32 * 128];
    const int tid = threadIdx.x;
    const int w = tid >> 6, ln = tid & 63;
    const int qt = blockIdx.x, h = blockIdx.y, b = blockIdx.z;
    const int hk = h >> 2;
    const int q0 = qt * 128;

    const bf16* qsec = Qp + ((size_t)(b*32 + h)*1024 + q0 + w*32)*64;
    const bf16* ksec = Kp + ((size_t)(b*8 + hk)*1024)*64;
    const bf16* vsec = Vt + ((size_t)(b*8 + hk))*64*1024;

    short8 qf[2][2];
    #pragma unroll
    for (int f = 0; f < 2; ++f)
        #pragma unroll
        for (int kc = 0; kc < 2; ++kc)
            qf[f][kc] = *(const short8*)(qsec + (size_t)(f*16 + (ln & 15))*64 + kc*32 + (ln >> 4)*8);

    f32x4 acc_o[2][4] = {};
    f32x4 m[2], l[2];
    #pragma unroll
    for (int f = 0; f < 2; ++f)
        #pragma unroll
        for (int j = 0; j < 4; ++j) { m[f][j] = -1e30f; l[f][j] = 0.0f; }

    const int lrow = ln >> 3;
    const int lkk  = (ln & 7) ^ lrow;
    char* PsW = (char*)Ps + w * 8192;

    const int ntiles = qt + 1;
    for (int kt = 0; kt < ntiles; ++kt) {
        const int kv0 = kt * 128;
        {
            const bf16* kbase = ksec + (size_t)(kv0 + w*32 + lrow)*64 + lkk*8;
            bf16* KsW = Ks + w*2048;
            #pragma unroll
            for (int i = 0; i < 4; ++i)
                __builtin_amdgcn_global_load_lds((cg_void*)(kbase + (size_t)i*8*64),
                                                 (lds_void*)(KsW + i*512), 16, 0, 0);
        }
        {
            bf16* VsW = Vs + w*2048;
            #pragma unroll
            for (int i = 0; i < 4; ++i) {
                int d = w*16 + i*4 + (ln >> 4);
                __builtin_amdgcn_global_load_lds(
                    (cg_void*)(vsec + (size_t)d*1024 + kv0 + (((ln & 15) ^ (d & 7))*8)),
                    (lds_void*)(VsW + i*512), 16, 0, 0);
            }
        }
        __syncthreads();

        f32x4 acc_s[2][8] = {};
        #pragma unroll
        for (int c = 0; c < 8; ++c) {
            int kvr = c*16 + (ln & 15);
            const char* krow = (const char*)Ks + kvr*128;
            short8 kf0 = *(const short8*)(krow + (((ln >> 4)*16)      ^ ((kvr & 7) << 4)));
            short8 kf1 = *(const short8*)(krow + ((64 + (ln >> 4)*16) ^ ((kvr & 7) << 4)));
            #pragma unroll
            for (int f = 0; f < 2; ++f) {
                acc_s[f][c] = __builtin_amdgcn_mfma_f32_16x16x32_bf16(qf[f][0], kf0, acc_s[f][c], 0, 0, 0);
                acc_s[f][c] = __builtin_amdgcn_mfma_f32_16x16x32_bf16(qf[f][1], kf1, acc_s[f][c], 0, 0, 0);
            }
        }

        const bool diag = (kt == qt);
        f32x4 vmax[2];
        #pragma unroll
        for (int f = 0; f < 2; ++f)
            #pragma unroll
            for (int j = 0; j < 4; ++j) vmax[f][j] = -1e30f;
        #pragma unroll
        for (int f = 0; f < 2; ++f) {
            #pragma unroll
            for (int c = 0; c < 8; ++c) {
                f32x4 t = acc_s[f][c] * 0.125f;
                if (diag) {
                    int kv = kv0 + c*16 + (ln & 15);
                    int qg = q0 + w*32 + f*16 + (ln >> 4)*4;
                    #pragma unroll
                    for (int j = 0; j < 4; ++j)
                        if (kv > qg + j) t[j] = -1e30f;
                }
                acc_s[f][c] = t;
                #pragma unroll
                for (int j = 0; j < 4; ++j) vmax[f][j] = fmaxf(vmax[f][j], t[j]);
            }
            #pragma unroll
            for (int mk = 1; mk <= 8; mk <<= 1)
                #pragma unroll
                for (int j = 0; j < 4; ++j)
                    vmax[f][j] = fmaxf(vmax[f][j], __shfl_xor(vmax[f][j], mk));
        }

        #pragma unroll
        for (int f = 0; f < 2; ++f) {
            f32x4 r;
            #pragma unroll
            for (int j = 0; j < 4; ++j) {
                float mn = fmaxf(m[f][j], vmax[f][j]);
                r[j] = __expf(m[f][j] - mn);
                m[f][j] = mn;
                l[f][j] *= r[j];
            }
            #pragma unroll
            for (int df = 0; df < 4; ++df)
                #pragma unroll
                for (int j = 0; j < 4; ++j) acc_o[f][df][j] *= r[j];
        }

        f32x4 rs[2] = {};
        #pragma unroll
        for (int f = 0; f < 2; ++f) {
            #pragma unroll
            for (int c = 0; c < 8; ++c) {
                #pragma unroll
                for (int j = 0; j < 4; ++j) {
                    float p = __expf(acc_s[f][c][j] - m[f][j]);
                    rs[f][j] += p;
                    int qloc = f*16 + (ln >> 4)*4 + j;
                    int kvb  = (c*16 + (ln & 15))*2;
                    *(bf16*)(PsW + qloc*256 + (kvb ^ ((qloc & 7) << 4))) = __float2bfloat16(p);
                }
            }
            #pragma unroll
            for (int mk = 1; mk <= 8; mk <<= 1)
                #pragma unroll
                for (int j = 0; j < 4; ++j)
                    rs[f][j] += __shfl_xor(rs[f][j], mk);
            #pragma unroll
            for (int j = 0; j < 4; ++j) l[f][j] += rs[f][j];
        }

        #pragma unroll
        for (int kc = 0; kc < 4; ++kc) {
            short8 pa[2];
            #pragma unroll
            for (int f = 0; f < 2; ++f) {
                int qloc = f*16 + (ln & 15);
                pa[f] = *(const short8*)(PsW + qloc*256 + ((kc*64 + (ln >> 4)*16) ^ ((qloc & 7) << 4)));
            }
            #pragma unroll
            for (int df = 0; df < 4; ++df) {
                int dl = df*16 + (ln & 15);
                short8 vfr = *(const short8*)((const char*)Vs + dl*256 + ((kc*64 + (ln >> 4)*16) ^ ((dl & 7) << 4)));
                #pragma unroll
                for (int f = 0; f < 2; ++f)
                    acc_o[f][df] = __builtin_amdgcn_mfma_f32_16x16x32_bf16(pa[f], vfr, acc_o[f][df], 0, 0, 0);
            }
        }
        __syncthreads();
    }

    #pragma unroll
    for (int f = 0; f < 2; ++f) {
        f32x4 inv;
        #pragma unroll
        for (int j = 0; j < 4; ++j) inv[j] = 1.0f / l[f][j];
        #pragma unroll
        for (int df = 0; df < 4; ++df) {
            #pragma unroll
            for (int j = 0; j < 4; ++j) {
                int q = q0 + w*32 + f*16 + (ln >> 4)*4 + j;
                int d = df*16 + (ln & 15);
                ctx[((size_t)b*1024 + q)*HID + h*64 + d] = __float2bfloat16(acc_o[f][df][j] * inv[j]);
            }
        }
    }
}

// ===================== launch ==============================================
extern "C" void kernel_launch(void* const* d_in, const int* in_sizes, int n_in,
                              void* d_out, int out_size, void* d_ws, size_t ws_size,
                              hipStream_t stream)
{
    const float* hidden = (const float*)d_in[0];
    const float* wq = (const float*)d_in[2];
    const float* wk = (const float*)d_in[3];
    const float* wv = (const float*)d_in[4];
    const float* wo = (const float*)d_in[5];
    const float* n1 = (const float*)d_in[6];
    const float* n2 = (const float*)d_in[7];
    const float* wg = (const float*)d_in[8];
    const float* wu = (const float*)d_in[9];
    const float* wd = (const float*)d_in[10];
    const int*  pos = (const int*)d_in[11];
    float* out = (float*)d_out;
    char* ws = (char*)d_ws;

    // workspace layout (byte offsets)
    bf16* wgu_t  = (bf16*)(ws + 0);           // [16384][2048] interleaved gate/up, 67.1 MB
    bf16* wd_t   = (bf16*)(ws + 67108864);    // [2048][8192]
    bf16* wqkv_t = (bf16*)(ws + 100663296);   // [3072][2048]
    bf16* wo_t   = (bf16*)(ws + 113246208);   // [2048][2048]
    bf16* normed = (bf16*)(ws + 121634816);   // [2048][2048]
    float* qkv   = (float*)(ws + 130023424);  // [2048][3072] f32
    bf16* ctx    = (bf16*)(ws + 155189248);   // [2048][2048]
    bf16* hb     = (bf16*)(ws + 130023424);   // [2048][8192] aliases qkv+ctx (dead in FFN)
    bf16* Qp     = (bf16*)(ws + 121634816);   // aliases normed (dead during attn)
    bf16* Kp     = (bf16*)(ws + 163577856);   // [16][1024][64]
    bf16* Vt     = (bf16*)(ws + 165675008);   // [16][64][1024]

    // weight casts
    cast_transpose<<<dim3(32, 32), 256, 0, stream>>>(wq, wqkv_t, 2048, 2048);
    cast_transpose<<<dim3(8, 32),  256, 0, stream>>>(wk, wqkv_t + 4194304, 2048, 512);
    cast_transpose<<<dim3(8, 32),  256, 0, stream>>>(wv, wqkv_t + 5242880, 2048, 512);
    cast_transpose<<<dim3(32, 32), 256, 0, stream>>>(wo, wo_t, 2048, 2048);
    cast_ilv<<<dim3(128, 32), 256, 0, stream>>>(wg, wgu_t, FFN_DIM, 0);
    cast_ilv<<<dim3(128, 32), 256, 0, stream>>>(wu, wgu_t, FFN_DIM, 1);
    cast_transpose<<<dim3(32, 128),256, 0, stream>>>(wd, wd_t, 8192, 2048);

    // 1. normed = rms_norm(hidden)
    rmsnorm_kernel<<<T_TOK, 256, 0, stream>>>(hidden, n1, normed);
    // 2. qkv = normed @ [wq|wk|wv] (f32)   grid 48x16 = 768 wg
    g_qkv<<<dim3(QKV_N/64, T_TOK/128), 256, 0, stream>>>(normed, wqkv_t, qkv);
    // 3. RoPE+cast; V transpose
    rope_cast<<<T_TOK, 256, 0, stream>>>(qkv, pos, Qp, Kp);
    vt_cast<<<dim3(16, 16), 256, 0, stream>>>(qkv, Vt);
    // 4. MFMA flash attention -> ctx (bf16)
    attn_mfma<<<dim3(8, NHEADS, 2), 256, 0, stream>>>(Qp, Kp, Vt, ctx);
    // 5. attn_out = ctx @ wo -> d_out (f32)   grid 32x16 = 512 wg
    g_wo<<<dim3(HID/64, T_TOK/128), 256, 0, stream>>>(ctx, wo_t, out);
    // 6. normed2 = rms_norm(attn_out + hidden)
    rmsnorm_add_kernel<<<T_TOK, 256, 0, stream>>>(out, hidden, n2, normed);
    // 7. hb = silu(normed @ wg) * (normed @ wu)  -- one fused GEMM, grid 128x16 = 2048 wg
    g_gateup<<<dim3(16384/128, T_TOK/128), 256, 0, stream>>>(normed, wgu_t, hb);
    // 8. d_out += hb @ wd   split-K=2, atomic f32 add; grid 32x16x2 = 1024 wg
    g_down<<<dim3(HID/64, T_TOK/128, 2), 256, 0, stream>>>(hb, wd_t, out);
}